// Round 1
// baseline (527.851 us; speedup 1.0000x reference)
//
#include <hip/hip_runtime.h>

typedef unsigned short u16;
typedef __attribute__((ext_vector_type(8))) __bf16 bf16x8;
typedef __attribute__((ext_vector_type(8))) unsigned short ushort8;
typedef __attribute__((ext_vector_type(4))) float f32x4;

#define MFMA16(a, b, c) __builtin_amdgcn_mfma_f32_16x16x32_bf16((a), (b), (c), 0, 0, 0)

__device__ __forceinline__ u16 f2bf(float f) {
  union { float f; unsigned u; } v; v.f = f;
  unsigned r = v.u + 0x7fffu + ((v.u >> 16) & 1u);
  return (u16)(r >> 16);
}

__device__ __forceinline__ void async16(const u16* g, u16* l) {
  __builtin_amdgcn_global_load_lds(
      (const __attribute__((address_space(1))) void*)g,
      (__attribute__((address_space(3))) void*)l, 16, 0, 0);
}

// ---------------- weight transpose fp32 [K][N] -> bf16 [N][K] ----------------
__global__ __launch_bounds__(256)
void transpose_bf16(const float* __restrict__ W, u16* __restrict__ Wt, int K, int N) {
  __shared__ float t[32][33];
  const int n0 = blockIdx.x * 32, k0 = blockIdx.y * 32;
  const int tx = threadIdx.x, ty = threadIdx.y;
  #pragma unroll
  for (int i = 0; i < 32; i += 8)
    t[ty + i][tx] = W[(size_t)(k0 + ty + i) * N + n0 + tx];
  __syncthreads();
  #pragma unroll
  for (int i = 0; i < 32; i += 8)
    Wt[(size_t)(n0 + ty + i) * K + k0 + tx] = f2bf(t[tx][ty + i]);
}

// ---------------- layernorm fp32 [4096][1024] -> bf16 ----------------
__global__ __launch_bounds__(256)
void ln_bf16(const float* __restrict__ X, const float* __restrict__ w,
             const float* __restrict__ bia, u16* __restrict__ out) {
  const int row = blockIdx.x, tid = threadIdx.x;
  const float4 v = ((const float4*)(X + (size_t)row * 1024))[tid];
  float s = v.x + v.y + v.z + v.w;
  float s2 = v.x * v.x + v.y * v.y + v.z * v.z + v.w * v.w;
  #pragma unroll
  for (int o = 32; o > 0; o >>= 1) { s += __shfl_down(s, o); s2 += __shfl_down(s2, o); }
  __shared__ float red[8];
  const int wv = tid >> 6, lane = tid & 63;
  if (lane == 0) { red[wv] = s; red[4 + wv] = s2; }
  __syncthreads();
  s = red[0] + red[1] + red[2] + red[3];
  s2 = red[4] + red[5] + red[6] + red[7];
  const float mean = s * (1.f / 1024.f);
  const float var = s2 * (1.f / 1024.f) - mean * mean;
  const float rstd = rsqrtf(var + 1e-5f);
  const float4 wv4 = ((const float4*)w)[tid];
  const float4 bv4 = ((const float4*)bia)[tid];
  ushort4 o;
  o.x = f2bf((v.x - mean) * rstd * wv4.x + bv4.x);
  o.y = f2bf((v.y - mean) * rstd * wv4.y + bv4.y);
  o.z = f2bf((v.z - mean) * rstd * wv4.z + bv4.z);
  o.w = f2bf((v.w - mean) * rstd * wv4.w + bv4.w);
  ((ushort4*)(out + (size_t)row * 1024))[tid] = o;
}

// ---------------- GEMM: C[M,N] = A[M,K] * Bt[N,K]^T, m97 structure ----------------
// MODE 0: qkv scatter (+bias) -> qo [B,H,T,d], ko [B,H,T,d], vo [B,H,d,T], bf16
// MODE 1: outF = resid + acc + bias (fp32)
// MODE 2: outB = gelu(acc + bias) (bf16)
// MODE 3: outF = resid + acc + bias (fp32)
template <int MODE>
__global__ __launch_bounds__(256)
void gemm_bt(const u16* __restrict__ A, const u16* __restrict__ Bt,
             const float* __restrict__ bias, const float* __restrict__ resid,
             float* __restrict__ outF, u16* __restrict__ outB,
             u16* __restrict__ qo, u16* __restrict__ ko, u16* __restrict__ vo,
             int M, int N, int K) {
  __shared__ u16 As[128 * 32];
  __shared__ u16 Bs[128 * 32];
  const int tid = threadIdx.x;
  const int lane = tid & 63, wv = tid >> 6;
  const int l16 = lane & 15, quad = lane >> 4;
  const int wr = wv >> 1, wc = wv & 1;
  const int m0 = blockIdx.y * 128, n0 = blockIdx.x * 128;
  const int srow = lane >> 2;        // 0..15 row within slot
  const int scol = (lane & 3) << 3;  // 0,8,16,24 elements

  f32x4 acc[4][4];
  const f32x4 fz = {0.f, 0.f, 0.f, 0.f};
  #pragma unroll
  for (int i = 0; i < 4; ++i)
    #pragma unroll
    for (int j = 0; j < 4; ++j) acc[i][j] = fz;

  for (int k0 = 0; k0 < K; k0 += 32) {
    __syncthreads();
    #pragma unroll
    for (int s = 0; s < 2; ++s) {
      const int slot = wv * 2 + s;  // 0..7, 16 rows each
      async16(A + (size_t)(m0 + slot * 16 + srow) * K + k0 + scol, As + slot * 512);
      async16(Bt + (size_t)(n0 + slot * 16 + srow) * K + k0 + scol, Bs + slot * 512);
    }
    __builtin_amdgcn_s_waitcnt(0xF70);  // vmcnt(0)
    __syncthreads();
    bf16x8 af[4], bfr[4];
    #pragma unroll
    for (int i = 0; i < 4; ++i)
      af[i] = *(const bf16x8*)(As + (wr * 64 + i * 16 + l16) * 32 + quad * 8);
    #pragma unroll
    for (int j = 0; j < 4; ++j)
      bfr[j] = *(const bf16x8*)(Bs + (wc * 64 + j * 16 + l16) * 32 + quad * 8);
    #pragma unroll
    for (int i = 0; i < 4; ++i)
      #pragma unroll
      for (int j = 0; j < 4; ++j)
        acc[i][j] = MFMA16(af[i], bfr[j], acc[i][j]);
  }

  #pragma unroll
  for (int i = 0; i < 4; ++i) {
    #pragma unroll
    for (int j = 0; j < 4; ++j) {
      const int col = n0 + wc * 64 + j * 16 + l16;
      const float bc = bias[col];
      #pragma unroll
      for (int r = 0; r < 4; ++r) {
        const int row = m0 + wr * 64 + i * 16 + quad * 4 + r;
        float v = acc[i][j][r] + bc;
        if (MODE == 0) {
          const int which = col >> 10, cc = col & 1023, hh = cc >> 6, dd = cc & 63;
          const int bb = row >> 11, t = row & 2047;
          const u16 bv = f2bf(v);
          if (which == 0)
            qo[((size_t)(bb * 16 + hh) * 2048 + t) * 64 + dd] = bv;
          else if (which == 1)
            ko[((size_t)(bb * 16 + hh) * 2048 + t) * 64 + dd] = bv;
          else
            vo[((size_t)(bb * 16 + hh) * 64 + dd) * 2048 + t] = bv;
        } else if (MODE == 1 || MODE == 3) {
          outF[(size_t)row * N + col] = resid[(size_t)row * N + col] + v;
        } else {
          const float x3 = v * v * v;
          const float u = 0.7978845608028654f * (v + 0.044715f * x3);
          const float e = __expf(2.f * u);
          const float th = 1.f - 2.f / (e + 1.f);
          outB[(size_t)row * N + col] = f2bf(0.5f * v * (1.f + th));
        }
      }
    }
  }
}

// ---------------- flash attention (causal), 1 block = (b,h, 128 q-rows) ----------------
// Q,K: [B*H][2048][64] bf16 ; V^T: [B*H][64][2048] bf16 ; ctx out: [B][2048][1024] bf16
__global__ __launch_bounds__(256)
void attn(const u16* __restrict__ Q, const u16* __restrict__ Kg,
          const u16* __restrict__ Vt, u16* __restrict__ ctx) {
  __shared__ u16 Ks[128 * 64];   // [key][64], 8-chunk xor-swizzled by key&7
  __shared__ u16 Vs[64 * 128];   // [d][128], 16-chunk xor-swizzled by d&15
  __shared__ u16 Ps[128 * 128];  // [q][128], 16-chunk xor-swizzled by q&15
  const int qt = blockIdx.x, bh = blockIdx.y;
  const int b = bh >> 4, h = bh & 15;
  const int tid = threadIdx.x;
  const int lane = tid & 63, wv = tid >> 6;
  const int l16 = lane & 15, quad = lane >> 4;
  const u16* Qb = Q + (size_t)bh * 2048 * 64;
  const u16* Kb = Kg + (size_t)bh * 2048 * 64;
  const u16* Vb = Vt + (size_t)bh * 64 * 2048;

  bf16x8 qf[2][2];
  #pragma unroll
  for (int i = 0; i < 2; ++i)
    #pragma unroll
    for (int c = 0; c < 2; ++c)
      qf[i][c] = *(const bf16x8*)(Qb + (size_t)(qt * 128 + wv * 32 + i * 16 + l16) * 64 +
                                  c * 32 + quad * 8);

  f32x4 octx[2][4];
  const f32x4 fz = {0.f, 0.f, 0.f, 0.f};
  #pragma unroll
  for (int i = 0; i < 2; ++i)
    #pragma unroll
    for (int jd = 0; jd < 4; ++jd) octx[i][jd] = fz;
  float mi[2][4], li[2][4];
  #pragma unroll
  for (int i = 0; i < 2; ++i)
    #pragma unroll
    for (int r = 0; r < 4; ++r) { mi[i][r] = -1e30f; li[i][r] = 0.f; }

  for (int kt = 0; kt <= qt; ++kt) {
    __syncthreads();  // previous iteration's LDS reads done
    // stage K and V^T tiles (swizzled ds_write_b128, coalesced global reads)
    #pragma unroll
    for (int s = 0; s < 4; ++s) {
      const int cid = tid + s * 256;  // 0..1023 chunk id
      {
        const int key = cid >> 3, ch = cid & 7;
        ushort8 d = *(const ushort8*)(Kb + (size_t)(kt * 128 + key) * 64 + ch * 8);
        *(ushort8*)(Ks + key * 64 + ((ch ^ (key & 7)) * 8)) = d;
      }
      {
        const int dd = cid >> 4, ch = cid & 15;
        ushort8 d = *(const ushort8*)(Vb + (size_t)dd * 2048 + kt * 128 + ch * 8);
        *(ushort8*)(Vs + dd * 128 + ((ch ^ (dd & 15)) * 8)) = d;
      }
    }
    __syncthreads();

    // S = Q K^T for this wave's 32 q-rows x 128 keys
    f32x4 sa[2][8];
    #pragma unroll
    for (int j = 0; j < 8; ++j) {
      const int key7 = l16 & 7;
      bf16x8 kf0 = *(const bf16x8*)(Ks + (16 * j + l16) * 64 + ((quad ^ key7) * 8));
      bf16x8 kf1 = *(const bf16x8*)(Ks + (16 * j + l16) * 64 + (((4 + quad) ^ key7) * 8));
      #pragma unroll
      for (int i = 0; i < 2; ++i) {
        f32x4 t = MFMA16(qf[i][0], kf0, fz);
        sa[i][j] = MFMA16(qf[i][1], kf1, t);
      }
    }
    if (kt == qt) {
      #pragma unroll
      for (int i = 0; i < 2; ++i)
        #pragma unroll
        for (int j = 0; j < 8; ++j)
          #pragma unroll
          for (int r = 0; r < 4; ++r) {
            const int rg = wv * 32 + i * 16 + quad * 4 + r;
            const int cg = j * 16 + l16;
            if (cg > rg) sa[i][j][r] = -1e30f;
          }
    }
    // online softmax (rows live across 16 lanes of each quad)
    #pragma unroll
    for (int i = 0; i < 2; ++i) {
      #pragma unroll
      for (int r = 0; r < 4; ++r) {
        float mx = -1e30f;
        #pragma unroll
        for (int j = 0; j < 8; ++j) mx = fmaxf(mx, sa[i][j][r]);
        mx = fmaxf(mx, __shfl_xor(mx, 1));
        mx = fmaxf(mx, __shfl_xor(mx, 2));
        mx = fmaxf(mx, __shfl_xor(mx, 4));
        mx = fmaxf(mx, __shfl_xor(mx, 8));
        mx *= 0.125f;
        const float mn = fmaxf(mi[i][r], mx);
        const float al = __expf(mi[i][r] - mn);
        mi[i][r] = mn;
        const int row = wv * 32 + i * 16 + quad * 4 + r;
        const int rl = row & 15;
        float rs = 0.f;
        #pragma unroll
        for (int j = 0; j < 8; ++j) {
          const float p = __expf(sa[i][j][r] * 0.125f - mn);
          rs += p;
          const int colc = 2 * j + (l16 >> 3);
          Ps[row * 128 + ((colc ^ rl) * 8) + (l16 & 7)] = f2bf(p);
        }
        rs += __shfl_xor(rs, 1);
        rs += __shfl_xor(rs, 2);
        rs += __shfl_xor(rs, 4);
        rs += __shfl_xor(rs, 8);
        li[i][r] = li[i][r] * al + rs;
        #pragma unroll
        for (int jd = 0; jd < 4; ++jd) octx[i][jd][r] *= al;
      }
    }
    __syncthreads();  // P writes ordered before P reads (wave-private rows, but be safe)
    // ctx += P V
    #pragma unroll
    for (int c = 0; c < 4; ++c) {
      bf16x8 pf[2];
      #pragma unroll
      for (int i = 0; i < 2; ++i) {
        const int row = wv * 32 + i * 16 + l16;
        pf[i] = *(const bf16x8*)(Ps + row * 128 + (((c * 4 + quad) ^ l16) * 8));
      }
      #pragma unroll
      for (int jd = 0; jd < 4; ++jd) {
        const int dd = jd * 16 + l16;
        bf16x8 vf = *(const bf16x8*)(Vs + dd * 128 + (((c * 4 + quad) ^ (dd & 15)) * 8));
        #pragma unroll
        for (int i = 0; i < 2; ++i) octx[i][jd] = MFMA16(pf[i], vf, octx[i][jd]);
      }
    }
  }
  // epilogue: ctx -> [B][T][H*d] bf16
  #pragma unroll
  for (int i = 0; i < 2; ++i)
    #pragma unroll
    for (int jd = 0; jd < 4; ++jd)
      #pragma unroll
      for (int r = 0; r < 4; ++r) {
        const int rowg = qt * 128 + wv * 32 + i * 16 + quad * 4 + r;
        const int col = h * 64 + jd * 16 + l16;
        ctx[((size_t)b * 2048 + rowg) * 1024 + col] = f2bf(octx[i][jd][r] / li[i][r]);
      }
}

// ---------------- launch ----------------
extern "C" void kernel_launch(void* const* d_in, const int* in_sizes, int n_in,
                              void* d_out, int out_size, void* d_ws, size_t ws_size,
                              hipStream_t stream) {
  (void)in_sizes; (void)n_in; (void)out_size; (void)ws_size;
  const float* x      = (const float*)d_in[0];
  const float* ln1_w  = (const float*)d_in[1];
  const float* ln1_b  = (const float*)d_in[2];
  const float* w_qkv  = (const float*)d_in[3];
  const float* b_qkv  = (const float*)d_in[4];
  const float* w_attn = (const float*)d_in[5];
  const float* b_attn = (const float*)d_in[6];
  const float* ln2_w  = (const float*)d_in[7];
  const float* ln2_b  = (const float*)d_in[8];
  const float* w_fc   = (const float*)d_in[9];
  const float* b_fc   = (const float*)d_in[10];
  const float* w_proj = (const float*)d_in[11];
  const float* b_proj = (const float*)d_in[12];
  float* out = (float*)d_out;

  char* ws = (char*)d_ws;
  size_t off = 0;
  auto alloc = [&](size_t n) {
    char* p = ws + off;
    off += (n + 255) & ~(size_t)255;
    return p;
  };
  u16* h1     = (u16*)alloc(4096ull * 1024 * 2);
  u16* wqkvT  = (u16*)alloc(3072ull * 1024 * 2);
  u16* wattnT = (u16*)alloc(1024ull * 1024 * 2);
  u16* wfcT   = (u16*)alloc(4096ull * 1024 * 2);
  u16* wprojT = (u16*)alloc(1024ull * 4096 * 2);
  u16* q      = (u16*)alloc(4096ull * 1024 * 2);
  u16* k      = (u16*)alloc(4096ull * 1024 * 2);
  u16* vT     = (u16*)alloc(4096ull * 1024 * 2);
  u16* ctxb   = (u16*)alloc(4096ull * 1024 * 2);
  float* out1 = (float*)alloc(4096ull * 1024 * 4);
  u16* h2     = (u16*)alloc(4096ull * 1024 * 2);
  u16* fco    = (u16*)alloc(4096ull * 4096 * 2);

  const dim3 tb(32, 8);
  transpose_bf16<<<dim3(3072 / 32, 1024 / 32), tb, 0, stream>>>(w_qkv, wqkvT, 1024, 3072);
  transpose_bf16<<<dim3(1024 / 32, 1024 / 32), tb, 0, stream>>>(w_attn, wattnT, 1024, 1024);
  transpose_bf16<<<dim3(4096 / 32, 1024 / 32), tb, 0, stream>>>(w_fc, wfcT, 1024, 4096);
  transpose_bf16<<<dim3(1024 / 32, 4096 / 32), tb, 0, stream>>>(w_proj, wprojT, 4096, 1024);

  ln_bf16<<<4096, 256, 0, stream>>>(x, ln1_w, ln1_b, h1);

  gemm_bt<0><<<dim3(24, 32), 256, 0, stream>>>(h1, wqkvT, b_qkv, nullptr, nullptr, nullptr,
                                               q, k, vT, 4096, 3072, 1024);

  attn<<<dim3(16, 32), 256, 0, stream>>>(q, k, vT, ctxb);

  gemm_bt<1><<<dim3(8, 32), 256, 0, stream>>>(ctxb, wattnT, b_attn, x, out1, nullptr,
                                              nullptr, nullptr, nullptr, 4096, 1024, 1024);

  ln_bf16<<<4096, 256, 0, stream>>>(out1, ln2_w, ln2_b, h2);

  gemm_bt<2><<<dim3(32, 32), 256, 0, stream>>>(h2, wfcT, b_fc, nullptr, nullptr, fco,
                                               nullptr, nullptr, nullptr, 4096, 4096, 1024);

  gemm_bt<3><<<dim3(8, 32), 256, 0, stream>>>(fco, wprojT, b_proj, out1, out, nullptr,
                                              nullptr, nullptr, nullptr, 4096, 1024, 4096);
}

// Round 2
// 414.173 us; speedup vs baseline: 1.2745x; 1.2745x over previous
//
#include <hip/hip_runtime.h>

typedef unsigned short u16;
typedef __attribute__((ext_vector_type(8))) __bf16 bf16x8;
typedef __attribute__((ext_vector_type(8))) unsigned short ushort8;
typedef __attribute__((ext_vector_type(4))) float f32x4;

#define MFMA16(a, b, c) __builtin_amdgcn_mfma_f32_16x16x32_bf16((a), (b), (c), 0, 0, 0)

__device__ __forceinline__ u16 f2bf(float f) {
  union { float f; unsigned u; } v; v.f = f;
  unsigned r = v.u + 0x7fffu + ((v.u >> 16) & 1u);
  return (u16)(r >> 16);
}

__device__ __forceinline__ void async16(const u16* g, u16* l) {
  __builtin_amdgcn_global_load_lds(
      (const __attribute__((address_space(1))) void*)g,
      (__attribute__((address_space(3))) void*)l, 16, 0, 0);
}

// ---------------- weight transpose fp32 [K][N] -> bf16 [N][K] ----------------
__global__ __launch_bounds__(256)
void transpose_bf16(const float* __restrict__ W, u16* __restrict__ Wt, int K, int N) {
  __shared__ float t[32][33];
  const int n0 = blockIdx.x * 32, k0 = blockIdx.y * 32;
  const int tx = threadIdx.x, ty = threadIdx.y;
  #pragma unroll
  for (int i = 0; i < 32; i += 8)
    t[ty + i][tx] = W[(size_t)(k0 + ty + i) * N + n0 + tx];
  __syncthreads();
  #pragma unroll
  for (int i = 0; i < 32; i += 8)
    Wt[(size_t)(n0 + ty + i) * K + k0 + tx] = f2bf(t[tx][ty + i]);
}

// ---------------- bf16 transpose for V: [B*H][2048][64] -> [B*H][64][2048] ----------------
__global__ __launch_bounds__(256)
void transpose_v(const u16* __restrict__ v, u16* __restrict__ vt) {
  __shared__ u16 t[64][72];  // pad to 144B row stride, 16B aligned
  const int bh = blockIdx.y, t0 = blockIdx.x * 64;
  const int tid = threadIdx.x;
  #pragma unroll
  for (int s = 0; s < 2; ++s) {
    const int idx = tid + s * 256;       // 0..511
    const int row = idx >> 3, ch = idx & 7;
    ushort8 d = *(const ushort8*)(v + ((size_t)bh * 2048 + t0 + row) * 64 + ch * 8);
    #pragma unroll
    for (int e = 0; e < 8; ++e) t[ch * 8 + e][row] = d[e];
  }
  __syncthreads();
  #pragma unroll
  for (int s = 0; s < 2; ++s) {
    const int idx = tid + s * 256;
    const int drow = idx >> 3, ch = idx & 7;
    ushort8 o = *(const ushort8*)(&t[drow][ch * 8]);
    *(ushort8*)(vt + ((size_t)bh * 64 + drow) * 2048 + t0 + ch * 8) = o;
  }
}

// ---------------- layernorm fp32 [4096][1024] -> bf16 ----------------
__global__ __launch_bounds__(256)
void ln_bf16(const float* __restrict__ X, const float* __restrict__ w,
             const float* __restrict__ bia, u16* __restrict__ out) {
  const int row = blockIdx.x, tid = threadIdx.x;
  const float4 v = ((const float4*)(X + (size_t)row * 1024))[tid];
  float s = v.x + v.y + v.z + v.w;
  float s2 = v.x * v.x + v.y * v.y + v.z * v.z + v.w * v.w;
  #pragma unroll
  for (int o = 32; o > 0; o >>= 1) { s += __shfl_down(s, o); s2 += __shfl_down(s2, o); }
  __shared__ float red[8];
  const int wv = tid >> 6, lane = tid & 63;
  if (lane == 0) { red[wv] = s; red[4 + wv] = s2; }
  __syncthreads();
  s = red[0] + red[1] + red[2] + red[3];
  s2 = red[4] + red[5] + red[6] + red[7];
  const float mean = s * (1.f / 1024.f);
  const float var = s2 * (1.f / 1024.f) - mean * mean;
  const float rstd = rsqrtf(var + 1e-5f);
  const float4 wv4 = ((const float4*)w)[tid];
  const float4 bv4 = ((const float4*)bia)[tid];
  ushort4 o;
  o.x = f2bf((v.x - mean) * rstd * wv4.x + bv4.x);
  o.y = f2bf((v.y - mean) * rstd * wv4.y + bv4.y);
  o.z = f2bf((v.z - mean) * rstd * wv4.z + bv4.z);
  o.w = f2bf((v.w - mean) * rstd * wv4.w + bv4.w);
  ((ushort4*)(out + (size_t)row * 1024))[tid] = o;
}

// ---------------- GEMM: C[M,N] = A[M,K] * Bt[N,K]^T, m97 structure ----------------
// MODE 0: qkv scatter (+bias) -> qo [B,H,T,d], ko [B,H,T,d], vo [B,H,T,d], bf16
// MODE 1/3: outF = resid + acc + bias (fp32)
// MODE 2: outB = gelu(acc + bias) (bf16)
template <int MODE>
__global__ __launch_bounds__(256)
void gemm_bt(const u16* __restrict__ A, const u16* __restrict__ Bt,
             const float* __restrict__ bias, const float* __restrict__ resid,
             float* __restrict__ outF, u16* __restrict__ outB,
             u16* __restrict__ qo, u16* __restrict__ ko, u16* __restrict__ vo,
             int M, int N, int K) {
  __shared__ u16 As[128 * 32];
  __shared__ u16 Bs[128 * 32];
  const int tid = threadIdx.x;
  const int lane = tid & 63, wv = tid >> 6;
  const int l16 = lane & 15, quad = lane >> 4;
  const int wr = wv >> 1, wc = wv & 1;
  const int m0 = blockIdx.y * 128, n0 = blockIdx.x * 128;
  const int srow = lane >> 2;
  const int scol = (lane & 3) << 3;

  f32x4 acc[4][4];
  const f32x4 fz = {0.f, 0.f, 0.f, 0.f};
  #pragma unroll
  for (int i = 0; i < 4; ++i)
    #pragma unroll
    for (int j = 0; j < 4; ++j) acc[i][j] = fz;

  for (int k0 = 0; k0 < K; k0 += 32) {
    __syncthreads();
    #pragma unroll
    for (int s = 0; s < 2; ++s) {
      const int slot = wv * 2 + s;
      async16(A + (size_t)(m0 + slot * 16 + srow) * K + k0 + scol, As + slot * 512);
      async16(Bt + (size_t)(n0 + slot * 16 + srow) * K + k0 + scol, Bs + slot * 512);
    }
    __builtin_amdgcn_s_waitcnt(0xF70);  // vmcnt(0)
    __syncthreads();
    bf16x8 af[4], bfr[4];
    #pragma unroll
    for (int i = 0; i < 4; ++i)
      af[i] = *(const bf16x8*)(As + (wr * 64 + i * 16 + l16) * 32 + quad * 8);
    #pragma unroll
    for (int j = 0; j < 4; ++j)
      bfr[j] = *(const bf16x8*)(Bs + (wc * 64 + j * 16 + l16) * 32 + quad * 8);
    #pragma unroll
    for (int i = 0; i < 4; ++i)
      #pragma unroll
      for (int j = 0; j < 4; ++j)
        acc[i][j] = MFMA16(af[i], bfr[j], acc[i][j]);
  }

  #pragma unroll
  for (int i = 0; i < 4; ++i) {
    #pragma unroll
    for (int j = 0; j < 4; ++j) {
      const int col = n0 + wc * 64 + j * 16 + l16;
      const float bc = bias[col];
      #pragma unroll
      for (int r = 0; r < 4; ++r) {
        const int row = m0 + wr * 64 + i * 16 + quad * 4 + r;
        float v = acc[i][j][r] + bc;
        if (MODE == 0) {
          const int which = col >> 10, cc = col & 1023, hh = cc >> 6, dd = cc & 63;
          const int bb = row >> 11, t = row & 2047;
          const u16 bv = f2bf(v);
          const size_t o = ((size_t)(bb * 16 + hh) * 2048 + t) * 64 + dd;
          if (which == 0) qo[o];
          if (which == 0)
            qo[o] = bv;
          else if (which == 1)
            ko[o] = bv;
          else
            vo[o] = bv;  // coalesced [B,H,T,d]; V^T built by transpose_v
        } else if (MODE == 1 || MODE == 3) {
          outF[(size_t)row * N + col] = resid[(size_t)row * N + col] + v;
        } else {
          const float x3 = v * v * v;
          const float u = 0.7978845608028654f * (v + 0.044715f * x3);
          const float e = __expf(2.f * u);
          const float th = 1.f - 2.f / (e + 1.f);
          outB[(size_t)row * N + col] = f2bf(0.5f * v * (1.f + th));
        }
      }
    }
  }
}

// ---------------- flash attention (causal), balanced pairing ----------------
// block = (b,h, pair p, half): 64 q-rows of BOTH q-tiles p and 15-p.
// Every block: 17 MFMA tile-iters, 16 stagings -> perfectly balanced.
// Q,K: [B*H][2048][64] bf16 ; V^T: [B*H][64][2048] bf16 ; ctx out: [B][2048][1024] bf16
__global__ __launch_bounds__(256)
void attn(const u16* __restrict__ Q, const u16* __restrict__ Kg,
          const u16* __restrict__ Vt, u16* __restrict__ ctx) {
  __shared__ u16 Ks[128 * 64];   // [key][64], 8-chunk xor-swizzled by key&7
  __shared__ u16 Vs[64 * 128];   // [d][128], 16-chunk xor-swizzled by d&15
  __shared__ u16 Ps[64 * 128];   // [local q][128], 16-chunk xor-swizzled by q&15
  const int px = blockIdx.x;               // 0..15
  const int pair = px >> 1, half = px & 1;
  const int qt0 = pair, qt1 = 15 - pair;   // qt0 <= 7 < 8 <= qt1
  const int bh = blockIdx.y;
  const int b = bh >> 4, h = bh & 15;
  const int tid = threadIdx.x;
  const int lane = tid & 63, wv = tid >> 6;
  const int l16 = lane & 15, quad = lane >> 4;
  const int rb = half * 64 + wv * 16;      // this wave's row base within a q-tile
  const u16* Qb = Q + (size_t)bh * 2048 * 64;
  const u16* Kb = Kg + (size_t)bh * 2048 * 64;
  const u16* Vb = Vt + (size_t)bh * 64 * 2048;

  bf16x8 qf[2][2];
  #pragma unroll
  for (int t = 0; t < 2; ++t)
    #pragma unroll
    for (int c = 0; c < 2; ++c)
      qf[t][c] = *(const bf16x8*)(Qb + (size_t)((t ? qt1 : qt0) * 128 + rb + l16) * 64 +
                                  c * 32 + quad * 8);

  f32x4 octx[2][4];
  const f32x4 fz = {0.f, 0.f, 0.f, 0.f};
  #pragma unroll
  for (int t = 0; t < 2; ++t)
    #pragma unroll
    for (int jd = 0; jd < 4; ++jd) octx[t][jd] = fz;
  float mi[2][4], li[2][4];
  #pragma unroll
  for (int t = 0; t < 2; ++t)
    #pragma unroll
    for (int r = 0; r < 4; ++r) { mi[t][r] = -1e30f; li[t][r] = 0.f; }

  for (int kt = 0; kt <= qt1; ++kt) {
    __syncthreads();  // previous iteration's K/V reads done
    #pragma unroll
    for (int s = 0; s < 4; ++s) {
      const int cid = tid + s * 256;  // 0..1023
      {
        const int key = cid >> 3, ch = cid & 7;
        ushort8 d = *(const ushort8*)(Kb + (size_t)(kt * 128 + key) * 64 + ch * 8);
        *(ushort8*)(Ks + key * 64 + ((ch ^ (key & 7)) * 8)) = d;
      }
      {
        const int dd = cid >> 4, ch = cid & 15;
        ushort8 d = *(const ushort8*)(Vb + (size_t)dd * 2048 + kt * 128 + ch * 8);
        *(ushort8*)(Vs + dd * 128 + ((ch ^ (dd & 15)) * 8)) = d;
      }
    }
    __syncthreads();

    #pragma unroll
    for (int t = 0; t < 2; ++t) {
      const int qt = t ? qt1 : qt0;
      if (kt > qt) continue;  // block-uniform

      // S = Q K^T for this wave's 16 q-rows x 128 keys
      f32x4 sa[8];
      #pragma unroll
      for (int j = 0; j < 8; ++j) {
        const int key7 = l16 & 7;
        bf16x8 kf0 = *(const bf16x8*)(Ks + (16 * j + l16) * 64 + ((quad ^ key7) * 8));
        bf16x8 kf1 = *(const bf16x8*)(Ks + (16 * j + l16) * 64 + (((4 + quad) ^ key7) * 8));
        f32x4 tt = MFMA16(qf[t][0], kf0, fz);
        sa[j] = MFMA16(qf[t][1], kf1, tt);
      }
      if (kt == qt) {
        #pragma unroll
        for (int j = 0; j < 8; ++j)
          #pragma unroll
          for (int r = 0; r < 4; ++r) {
            const int rg = rb + quad * 4 + r;
            const int cg = j * 16 + l16;
            if (cg > rg) sa[j][r] = -1e30f;
          }
      }
      // online softmax (each row lives across the 16 lanes of a quad)
      #pragma unroll
      for (int r = 0; r < 4; ++r) {
        float mx = -1e30f;
        #pragma unroll
        for (int j = 0; j < 8; ++j) mx = fmaxf(mx, sa[j][r]);
        mx = fmaxf(mx, __shfl_xor(mx, 1));
        mx = fmaxf(mx, __shfl_xor(mx, 2));
        mx = fmaxf(mx, __shfl_xor(mx, 4));
        mx = fmaxf(mx, __shfl_xor(mx, 8));
        mx *= 0.125f;
        const float mn = fmaxf(mi[t][r], mx);
        const float al = __expf(mi[t][r] - mn);
        mi[t][r] = mn;
        const int row = wv * 16 + quad * 4 + r;  // local row 0..63
        const int rl = row & 15;
        float rs = 0.f;
        #pragma unroll
        for (int j = 0; j < 8; ++j) {
          const float p = __expf(sa[j][r] * 0.125f - mn);
          rs += p;
          const int colc = 2 * j + (l16 >> 3);
          Ps[row * 128 + ((colc ^ rl) * 8) + (l16 & 7)] = f2bf(p);
        }
        rs += __shfl_xor(rs, 1);
        rs += __shfl_xor(rs, 2);
        rs += __shfl_xor(rs, 4);
        rs += __shfl_xor(rs, 8);
        li[t][r] = li[t][r] * al + rs;
        #pragma unroll
        for (int jd = 0; jd < 4; ++jd) octx[t][jd][r] *= al;
      }
      // ctx += P V  (wave reads only its own Ps rows; same-wave ordering, no barrier)
      #pragma unroll
      for (int c = 0; c < 4; ++c) {
        const int row = wv * 16 + l16;
        bf16x8 pf = *(const bf16x8*)(Ps + row * 128 + (((c * 4 + quad) ^ l16) * 8));
        #pragma unroll
        for (int jd = 0; jd < 4; ++jd) {
          const int dd = jd * 16 + l16;
          bf16x8 vf = *(const bf16x8*)(Vs + dd * 128 + (((c * 4 + quad) ^ (dd & 15)) * 8));
          octx[t][jd] = MFMA16(pf, vf, octx[t][jd]);
        }
      }
    }
  }
  // epilogue: ctx -> [B][T][H*d] bf16
  #pragma unroll
  for (int t = 0; t < 2; ++t) {
    const int qt = t ? qt1 : qt0;
    #pragma unroll
    for (int jd = 0; jd < 4; ++jd)
      #pragma unroll
      for (int r = 0; r < 4; ++r) {
        const int rowg = qt * 128 + rb + quad * 4 + r;
        const int col = h * 64 + jd * 16 + l16;
        ctx[((size_t)b * 2048 + rowg) * 1024 + col] = f2bf(octx[t][jd][r] / li[t][r]);
      }
  }
}

// ---------------- launch ----------------
extern "C" void kernel_launch(void* const* d_in, const int* in_sizes, int n_in,
                              void* d_out, int out_size, void* d_ws, size_t ws_size,
                              hipStream_t stream) {
  (void)in_sizes; (void)n_in; (void)out_size; (void)ws_size;
  const float* x      = (const float*)d_in[0];
  const float* ln1_w  = (const float*)d_in[1];
  const float* ln1_b  = (const float*)d_in[2];
  const float* w_qkv  = (const float*)d_in[3];
  const float* b_qkv  = (const float*)d_in[4];
  const float* w_attn = (const float*)d_in[5];
  const float* b_attn = (const float*)d_in[6];
  const float* ln2_w  = (const float*)d_in[7];
  const float* ln2_b  = (const float*)d_in[8];
  const float* w_fc   = (const float*)d_in[9];
  const float* b_fc   = (const float*)d_in[10];
  const float* w_proj = (const float*)d_in[11];
  const float* b_proj = (const float*)d_in[12];
  float* out = (float*)d_out;

  char* ws = (char*)d_ws;
  size_t off = 0;
  auto alloc = [&](size_t n) {
    char* p = ws + off;
    off += (n + 255) & ~(size_t)255;
    return p;
  };
  u16* h1     = (u16*)alloc(4096ull * 1024 * 2);
  u16* wqkvT  = (u16*)alloc(3072ull * 1024 * 2);
  u16* wattnT = (u16*)alloc(1024ull * 1024 * 2);
  u16* wfcT   = (u16*)alloc(4096ull * 1024 * 2);
  u16* wprojT = (u16*)alloc(1024ull * 4096 * 2);
  u16* q      = (u16*)alloc(4096ull * 1024 * 2);
  u16* k      = (u16*)alloc(4096ull * 1024 * 2);
  u16* vT     = (u16*)alloc(4096ull * 1024 * 2);
  u16* ctxb   = (u16*)alloc(4096ull * 1024 * 2);  // doubles as raw-V temp pre-attn
  float* out1 = (float*)alloc(4096ull * 1024 * 4);
  u16* h2     = (u16*)alloc(4096ull * 1024 * 2);
  u16* fco    = (u16*)alloc(4096ull * 4096 * 2);

  u16* vtmp = ctxb;  // dead until attn runs; reuse as raw V [B,H,T,d]

  const dim3 tb(32, 8);
  transpose_bf16<<<dim3(3072 / 32, 1024 / 32), tb, 0, stream>>>(w_qkv, wqkvT, 1024, 3072);
  transpose_bf16<<<dim3(1024 / 32, 1024 / 32), tb, 0, stream>>>(w_attn, wattnT, 1024, 1024);
  transpose_bf16<<<dim3(4096 / 32, 1024 / 32), tb, 0, stream>>>(w_fc, wfcT, 1024, 4096);
  transpose_bf16<<<dim3(1024 / 32, 4096 / 32), tb, 0, stream>>>(w_proj, wprojT, 4096, 1024);

  ln_bf16<<<4096, 256, 0, stream>>>(x, ln1_w, ln1_b, h1);

  gemm_bt<0><<<dim3(24, 32), 256, 0, stream>>>(h1, wqkvT, b_qkv, nullptr, nullptr, nullptr,
                                               q, k, vtmp, 4096, 3072, 1024);

  transpose_v<<<dim3(32, 32), 256, 0, stream>>>(vtmp, vT);

  attn<<<dim3(16, 32), 256, 0, stream>>>(q, k, vT, ctxb);

  gemm_bt<1><<<dim3(8, 32), 256, 0, stream>>>(ctxb, wattnT, b_attn, x, out1, nullptr,
                                              nullptr, nullptr, nullptr, 4096, 1024, 1024);

  ln_bf16<<<4096, 256, 0, stream>>>(out1, ln2_w, ln2_b, h2);

  gemm_bt<2><<<dim3(32, 32), 256, 0, stream>>>(h2, wfcT, b_fc, nullptr, nullptr, fco,
                                               nullptr, nullptr, nullptr, 4096, 4096, 1024);

  gemm_bt<3><<<dim3(8, 32), 256, 0, stream>>>(fco, wprojT, b_proj, out1, out, nullptr,
                                              nullptr, nullptr, nullptr, 4096, 1024, 4096);
}

// Round 3
// 383.786 us; speedup vs baseline: 1.3754x; 1.0792x over previous
//
#include <hip/hip_runtime.h>

typedef unsigned short u16;
typedef __attribute__((ext_vector_type(8))) __bf16 bf16x8;
typedef __attribute__((ext_vector_type(8))) unsigned short ushort8;
typedef __attribute__((ext_vector_type(4))) float f32x4;

#define MFMA16(a, b, c) __builtin_amdgcn_mfma_f32_16x16x32_bf16((a), (b), (c), 0, 0, 0)

__device__ __forceinline__ u16 f2bf(float f) {
  union { float f; unsigned u; } v; v.f = f;
  unsigned r = v.u + 0x7fffu + ((v.u >> 16) & 1u);
  return (u16)(r >> 16);
}

__device__ __forceinline__ void async16(const u16* g, u16* l) {
  __builtin_amdgcn_global_load_lds(
      (const __attribute__((address_space(1))) void*)g,
      (__attribute__((address_space(3))) void*)l, 16, 0, 0);
}

// ---------------- weight transpose fp32 [K][N] -> bf16 [N][K] ----------------
__global__ __launch_bounds__(256)
void transpose_bf16(const float* __restrict__ W, u16* __restrict__ Wt, int K, int N) {
  __shared__ float t[32][33];
  const int n0 = blockIdx.x * 32, k0 = blockIdx.y * 32;
  const int tx = threadIdx.x, ty = threadIdx.y;
  #pragma unroll
  for (int i = 0; i < 32; i += 8)
    t[ty + i][tx] = W[(size_t)(k0 + ty + i) * N + n0 + tx];
  __syncthreads();
  #pragma unroll
  for (int i = 0; i < 32; i += 8)
    Wt[(size_t)(n0 + ty + i) * K + k0 + tx] = f2bf(t[tx][ty + i]);
}

// ---------------- bf16 transpose for V: [B*H][2048][64] -> [B*H][64][2048] ----------------
__global__ __launch_bounds__(256)
void transpose_v(const u16* __restrict__ v, u16* __restrict__ vt) {
  __shared__ u16 t[64][72];
  const int bh = blockIdx.y, t0 = blockIdx.x * 64;
  const int tid = threadIdx.x;
  #pragma unroll
  for (int s = 0; s < 2; ++s) {
    const int idx = tid + s * 256;
    const int row = idx >> 3, ch = idx & 7;
    ushort8 d = *(const ushort8*)(v + ((size_t)bh * 2048 + t0 + row) * 64 + ch * 8);
    #pragma unroll
    for (int e = 0; e < 8; ++e) t[ch * 8 + e][row] = d[e];
  }
  __syncthreads();
  #pragma unroll
  for (int s = 0; s < 2; ++s) {
    const int idx = tid + s * 256;
    const int drow = idx >> 3, ch = idx & 7;
    ushort8 o = *(const ushort8*)(&t[drow][ch * 8]);
    *(ushort8*)(vt + ((size_t)bh * 64 + drow) * 2048 + t0 + ch * 8) = o;
  }
}

// ---------------- layernorm fp32 [4096][1024] -> bf16 ----------------
__global__ __launch_bounds__(256)
void ln_bf16(const float* __restrict__ X, const float* __restrict__ w,
             const float* __restrict__ bia, u16* __restrict__ out) {
  const int row = blockIdx.x, tid = threadIdx.x;
  const float4 v = ((const float4*)(X + (size_t)row * 1024))[tid];
  float s = v.x + v.y + v.z + v.w;
  float s2 = v.x * v.x + v.y * v.y + v.z * v.z + v.w * v.w;
  #pragma unroll
  for (int o = 32; o > 0; o >>= 1) { s += __shfl_down(s, o); s2 += __shfl_down(s2, o); }
  __shared__ float red[8];
  const int wv = tid >> 6, lane = tid & 63;
  if (lane == 0) { red[wv] = s; red[4 + wv] = s2; }
  __syncthreads();
  s = red[0] + red[1] + red[2] + red[3];
  s2 = red[4] + red[5] + red[6] + red[7];
  const float mean = s * (1.f / 1024.f);
  const float var = s2 * (1.f / 1024.f) - mean * mean;
  const float rstd = rsqrtf(var + 1e-5f);
  const float4 wv4 = ((const float4*)w)[tid];
  const float4 bv4 = ((const float4*)bia)[tid];
  ushort4 o;
  o.x = f2bf((v.x - mean) * rstd * wv4.x + bv4.x);
  o.y = f2bf((v.y - mean) * rstd * wv4.y + bv4.y);
  o.z = f2bf((v.z - mean) * rstd * wv4.z + bv4.z);
  o.w = f2bf((v.w - mean) * rstd * wv4.w + bv4.w);
  ((ushort4*)(out + (size_t)row * 1024))[tid] = o;
}

// ---------------- GEMM: C[M,N] = A[M,K] * Bt[N,K]^T ----------------
// BK=64, 128B LDS rows, XOR-8 chunk swizzle (conflict-free phase groups).
// MODE 0: qkv scatter (+bias) -> qo/ko/vo [B,H,T,d] bf16
// MODE 1: outF = resid + acc + bias (fp32)
// MODE 2: outB = gelu(acc + bias) (bf16)
// MODE 4: outF[z*M*N + ...] = acc (fp32 partial, split-K)
template <int MODE>
__global__ __launch_bounds__(256)
void gemm_bt(const u16* __restrict__ A, const u16* __restrict__ Bt,
             const float* __restrict__ bias, const float* __restrict__ resid,
             float* __restrict__ outF, u16* __restrict__ outB,
             u16* __restrict__ qo, u16* __restrict__ ko, u16* __restrict__ vo,
             int M, int N, int K, int kSlice) {
  __shared__ u16 As[128 * 64];
  __shared__ u16 Bs[128 * 64];
  const int tid = threadIdx.x;
  const int lane = tid & 63, wv = tid >> 6;
  const int l16 = lane & 15, quad = lane >> 4;
  const int wr = wv >> 1, wc = wv & 1;
  const int m0 = blockIdx.y * 128, n0 = blockIdx.x * 128;
  const int kBegin = blockIdx.z * kSlice, kEnd = kBegin + kSlice;
  // staging: lane -> (row srow, permuted 16B chunk sch) within an 8-row group
  const int srow = lane >> 3;
  const int sch = (lane & 7) ^ srow;

  f32x4 acc[4][4];
  const f32x4 fz = {0.f, 0.f, 0.f, 0.f};
  #pragma unroll
  for (int i = 0; i < 4; ++i)
    #pragma unroll
    for (int j = 0; j < 4; ++j) acc[i][j] = fz;

  for (int k0 = kBegin; k0 < kEnd; k0 += 64) {
    __syncthreads();
    #pragma unroll
    for (int s = 0; s < 4; ++s) {
      const int R = wv * 32 + s * 8;  // wave-uniform row base (8 rows per call)
      async16(A + (size_t)(m0 + R + srow) * K + k0 + sch * 8, As + R * 64);
      async16(Bt + (size_t)(n0 + R + srow) * K + k0 + sch * 8, Bs + R * 64);
    }
    __builtin_amdgcn_s_waitcnt(0xF70);  // vmcnt(0)
    __syncthreads();
    #pragma unroll
    for (int h = 0; h < 2; ++h) {
      bf16x8 af[4], bfr[4];
      #pragma unroll
      for (int i = 0; i < 4; ++i) {
        const int row = wr * 64 + i * 16 + l16;
        af[i] = *(const bf16x8*)(As + row * 64 + (((h * 4 + quad) ^ (l16 & 7)) * 8));
      }
      #pragma unroll
      for (int j = 0; j < 4; ++j) {
        const int row = wc * 64 + j * 16 + l16;
        bfr[j] = *(const bf16x8*)(Bs + row * 64 + (((h * 4 + quad) ^ (l16 & 7)) * 8));
      }
      #pragma unroll
      for (int i = 0; i < 4; ++i)
        #pragma unroll
        for (int j = 0; j < 4; ++j)
          acc[i][j] = MFMA16(af[i], bfr[j], acc[i][j]);
    }
  }

  #pragma unroll
  for (int i = 0; i < 4; ++i) {
    #pragma unroll
    for (int j = 0; j < 4; ++j) {
      const int col = n0 + wc * 64 + j * 16 + l16;
      const float bc = bias[col];
      #pragma unroll
      for (int r = 0; r < 4; ++r) {
        const int row = m0 + wr * 64 + i * 16 + quad * 4 + r;
        float v = acc[i][j][r];
        if (MODE != 4) v += bc;
        if (MODE == 0) {
          const int which = col >> 10, cc = col & 1023, hh = cc >> 6, dd = cc & 63;
          const int bb = row >> 11, t = row & 2047;
          const u16 bv = f2bf(v);
          const size_t o = ((size_t)(bb * 16 + hh) * 2048 + t) * 64 + dd;
          if (which == 0)
            qo[o] = bv;
          else if (which == 1)
            ko[o] = bv;
          else
            vo[o] = bv;
        } else if (MODE == 1) {
          outF[(size_t)row * N + col] = resid[(size_t)row * N + col] + v;
        } else if (MODE == 2) {
          const float x3 = v * v * v;
          const float u = 0.7978845608028654f * (v + 0.044715f * x3);
          const float e = __expf(2.f * u);
          const float th = 1.f - 2.f / (e + 1.f);
          outB[(size_t)row * N + col] = f2bf(0.5f * v * (1.f + th));
        } else {  // MODE 4: split-K partial
          outF[(size_t)blockIdx.z * M * N + (size_t)row * N + col] = v;
        }
      }
    }
  }
}

// ---------------- split-K reduce: out = resid + bias + P0 + P1 ----------------
__global__ __launch_bounds__(256)
void reduce2(const float* __restrict__ P, const float* __restrict__ resid,
             const float* __restrict__ bias, float* __restrict__ out, int MN, int N) {
  const int idx4 = blockIdx.x * 256 + threadIdx.x;  // float4 index
  const size_t s = (size_t)MN >> 2;
  const float4 a = ((const float4*)P)[idx4];
  const float4 b = ((const float4*)P)[idx4 + s];
  const float4 r = ((const float4*)resid)[idx4];
  const float4 bb = ((const float4*)bias)[idx4 & (N / 4 - 1)];
  float4 o;
  o.x = r.x + a.x + b.x + bb.x;
  o.y = r.y + a.y + b.y + bb.y;
  o.z = r.z + a.z + b.z + bb.z;
  o.w = r.w + a.w + b.w + bb.w;
  ((float4*)out)[idx4] = o;
}

// ---------------- flash attention (causal), balanced pairing ----------------
__global__ __launch_bounds__(256)
void attn(const u16* __restrict__ Q, const u16* __restrict__ Kg,
          const u16* __restrict__ Vt, u16* __restrict__ ctx) {
  __shared__ u16 Ks[128 * 64];   // [key][64], 8-chunk xor-swizzled by key&7
  __shared__ u16 Vs[64 * 128];   // [d][128], 16-chunk xor-swizzled by d&15
  __shared__ u16 Ps[64 * 128];   // [local q][128], 16-chunk xor-swizzled by q&15
  const int px = blockIdx.x;
  const int pair = px >> 1, half = px & 1;
  const int qt0 = pair, qt1 = 15 - pair;
  const int bh = blockIdx.y;
  const int b = bh >> 4, h = bh & 15;
  const int tid = threadIdx.x;
  const int lane = tid & 63, wv = tid >> 6;
  const int l16 = lane & 15, quad = lane >> 4;
  const int rb = half * 64 + wv * 16;
  const u16* Qb = Q + (size_t)bh * 2048 * 64;
  const u16* Kb = Kg + (size_t)bh * 2048 * 64;
  const u16* Vb = Vt + (size_t)bh * 64 * 2048;

  bf16x8 qf[2][2];
  #pragma unroll
  for (int t = 0; t < 2; ++t)
    #pragma unroll
    for (int c = 0; c < 2; ++c)
      qf[t][c] = *(const bf16x8*)(Qb + (size_t)((t ? qt1 : qt0) * 128 + rb + l16) * 64 +
                                  c * 32 + quad * 8);

  f32x4 octx[2][4];
  const f32x4 fz = {0.f, 0.f, 0.f, 0.f};
  #pragma unroll
  for (int t = 0; t < 2; ++t)
    #pragma unroll
    for (int jd = 0; jd < 4; ++jd) octx[t][jd] = fz;
  float mi[2][4], li[2][4];
  #pragma unroll
  for (int t = 0; t < 2; ++t)
    #pragma unroll
    for (int r = 0; r < 4; ++r) { mi[t][r] = -1e30f; li[t][r] = 0.f; }

  for (int kt = 0; kt <= qt1; ++kt) {
    __syncthreads();
    #pragma unroll
    for (int s = 0; s < 4; ++s) {
      const int cid = tid + s * 256;
      {
        const int key = cid >> 3, ch = cid & 7;
        ushort8 d = *(const ushort8*)(Kb + (size_t)(kt * 128 + key) * 64 + ch * 8);
        *(ushort8*)(Ks + key * 64 + ((ch ^ (key & 7)) * 8)) = d;
      }
      {
        const int dd = cid >> 4, ch = cid & 15;
        ushort8 d = *(const ushort8*)(Vb + (size_t)dd * 2048 + kt * 128 + ch * 8);
        *(ushort8*)(Vs + dd * 128 + ((ch ^ (dd & 15)) * 8)) = d;
      }
    }
    __syncthreads();

    #pragma unroll
    for (int t = 0; t < 2; ++t) {
      const int qt = t ? qt1 : qt0;
      if (kt > qt) continue;

      f32x4 sa[8];
      #pragma unroll
      for (int j = 0; j < 8; ++j) {
        const int key7 = l16 & 7;
        bf16x8 kf0 = *(const bf16x8*)(Ks + (16 * j + l16) * 64 + ((quad ^ key7) * 8));
        bf16x8 kf1 = *(const bf16x8*)(Ks + (16 * j + l16) * 64 + (((4 + quad) ^ key7) * 8));
        f32x4 tt = MFMA16(qf[t][0], kf0, fz);
        sa[j] = MFMA16(qf[t][1], kf1, tt);
      }
      if (kt == qt) {
        #pragma unroll
        for (int j = 0; j < 8; ++j)
          #pragma unroll
          for (int r = 0; r < 4; ++r) {
            const int rg = rb + quad * 4 + r;
            const int cg = j * 16 + l16;
            if (cg > rg) sa[j][r] = -1e30f;
          }
      }
      #pragma unroll
      for (int r = 0; r < 4; ++r) {
        float mx = -1e30f;
        #pragma unroll
        for (int j = 0; j < 8; ++j) mx = fmaxf(mx, sa[j][r]);
        mx = fmaxf(mx, __shfl_xor(mx, 1));
        mx = fmaxf(mx, __shfl_xor(mx, 2));
        mx = fmaxf(mx, __shfl_xor(mx, 4));
        mx = fmaxf(mx, __shfl_xor(mx, 8));
        mx *= 0.125f;
        const float mn = fmaxf(mi[t][r], mx);
        const float al = __expf(mi[t][r] - mn);
        mi[t][r] = mn;
        const int row = wv * 16 + quad * 4 + r;
        const int rl = row & 15;
        float rs = 0.f;
        #pragma unroll
        for (int j = 0; j < 8; ++j) {
          const float p = __expf(sa[j][r] * 0.125f - mn);
          rs += p;
          const int colc = 2 * j + (l16 >> 3);
          Ps[row * 128 + ((colc ^ rl) * 8) + (l16 & 7)] = f2bf(p);
        }
        rs += __shfl_xor(rs, 1);
        rs += __shfl_xor(rs, 2);
        rs += __shfl_xor(rs, 4);
        rs += __shfl_xor(rs, 8);
        li[t][r] = li[t][r] * al + rs;
        #pragma unroll
        for (int jd = 0; jd < 4; ++jd) octx[t][jd][r] *= al;
      }
      #pragma unroll
      for (int c = 0; c < 4; ++c) {
        const int row = wv * 16 + l16;
        bf16x8 pf = *(const bf16x8*)(Ps + row * 128 + (((c * 4 + quad) ^ l16) * 8));
        #pragma unroll
        for (int jd = 0; jd < 4; ++jd) {
          const int dd = jd * 16 + l16;
          bf16x8 vf = *(const bf16x8*)(Vs + dd * 128 + (((c * 4 + quad) ^ (dd & 15)) * 8));
          octx[t][jd] = MFMA16(pf, vf, octx[t][jd]);
        }
      }
    }
  }
  #pragma unroll
  for (int t = 0; t < 2; ++t) {
    const int qt = t ? qt1 : qt0;
    #pragma unroll
    for (int jd = 0; jd < 4; ++jd)
      #pragma unroll
      for (int r = 0; r < 4; ++r) {
        const int rowg = qt * 128 + rb + quad * 4 + r;
        const int col = h * 64 + jd * 16 + l16;
        ctx[((size_t)b * 2048 + rowg) * 1024 + col] = f2bf(octx[t][jd][r] / li[t][r]);
      }
  }
}

// ---------------- launch ----------------
extern "C" void kernel_launch(void* const* d_in, const int* in_sizes, int n_in,
                              void* d_out, int out_size, void* d_ws, size_t ws_size,
                              hipStream_t stream) {
  (void)in_sizes; (void)n_in; (void)out_size; (void)ws_size;
  const float* x      = (const float*)d_in[0];
  const float* ln1_w  = (const float*)d_in[1];
  const float* ln1_b  = (const float*)d_in[2];
  const float* w_qkv  = (const float*)d_in[3];
  const float* b_qkv  = (const float*)d_in[4];
  const float* w_attn = (const float*)d_in[5];
  const float* b_attn = (const float*)d_in[6];
  const float* ln2_w  = (const float*)d_in[7];
  const float* ln2_b  = (const float*)d_in[8];
  const float* w_fc   = (const float*)d_in[9];
  const float* b_fc   = (const float*)d_in[10];
  const float* w_proj = (const float*)d_in[11];
  const float* b_proj = (const float*)d_in[12];
  float* out = (float*)d_out;

  char* ws = (char*)d_ws;
  size_t off = 0;
  auto alloc = [&](size_t n) {
    char* p = ws + off;
    off += (n + 255) & ~(size_t)255;
    return p;
  };
  u16* h1     = (u16*)alloc(4096ull * 1024 * 2);
  u16* wqkvT  = (u16*)alloc(3072ull * 1024 * 2);
  u16* wattnT = (u16*)alloc(1024ull * 1024 * 2);
  u16* wfcT   = (u16*)alloc(4096ull * 1024 * 2);
  u16* wprojT = (u16*)alloc(1024ull * 4096 * 2);
  u16* q      = (u16*)alloc(4096ull * 1024 * 2);
  u16* k      = (u16*)alloc(4096ull * 1024 * 2);
  u16* vT     = (u16*)alloc(4096ull * 1024 * 2);
  u16* ctxb   = (u16*)alloc(4096ull * 1024 * 2);
  float* out1 = (float*)alloc(4096ull * 1024 * 4);
  u16* h2     = (u16*)alloc(4096ull * 1024 * 2);
  u16* fco    = (u16*)alloc(4096ull * 4096 * 2);

  u16* vtmp = ctxb;             // dead until attn; raw V [B,H,T,d]
  float* projP = (float*)q;     // q..ctxb (32 MB) dead after attn-proj: split-K partials

  const dim3 tb(32, 8);
  transpose_bf16<<<dim3(3072 / 32, 1024 / 32), tb, 0, stream>>>(w_qkv, wqkvT, 1024, 3072);
  transpose_bf16<<<dim3(1024 / 32, 1024 / 32), tb, 0, stream>>>(w_attn, wattnT, 1024, 1024);
  transpose_bf16<<<dim3(4096 / 32, 1024 / 32), tb, 0, stream>>>(w_fc, wfcT, 1024, 4096);
  transpose_bf16<<<dim3(1024 / 32, 4096 / 32), tb, 0, stream>>>(w_proj, wprojT, 4096, 1024);

  ln_bf16<<<4096, 256, 0, stream>>>(x, ln1_w, ln1_b, h1);

  gemm_bt<0><<<dim3(24, 32, 1), 256, 0, stream>>>(h1, wqkvT, b_qkv, nullptr, nullptr,
                                                  nullptr, q, k, vtmp, 4096, 3072, 1024, 1024);

  transpose_v<<<dim3(32, 32), 256, 0, stream>>>(vtmp, vT);

  attn<<<dim3(16, 32), 256, 0, stream>>>(q, k, vT, ctxb);

  gemm_bt<1><<<dim3(8, 32, 1), 256, 0, stream>>>(ctxb, wattnT, b_attn, x, out1, nullptr,
                                                 nullptr, nullptr, nullptr, 4096, 1024, 1024, 1024);

  ln_bf16<<<4096, 256, 0, stream>>>(out1, ln2_w, ln2_b, h2);

  gemm_bt<2><<<dim3(32, 32, 1), 256, 0, stream>>>(h2, wfcT, b_fc, nullptr, nullptr, fco,
                                                  nullptr, nullptr, nullptr, 4096, 4096, 1024, 1024);

  // proj: split-K=2 partials (no bias), then fused reduce + bias + residual
  gemm_bt<4><<<dim3(8, 32, 2), 256, 0, stream>>>(fco, wprojT, b_proj, nullptr, projP, nullptr,
                                                 nullptr, nullptr, nullptr, 4096, 1024, 4096, 2048);

  reduce2<<<4096, 256, 0, stream>>>(projP, out1, b_proj, out, 4096 * 1024, 1024);
}

// Round 4
// 373.695 us; speedup vs baseline: 1.4125x; 1.0270x over previous
//
#include <hip/hip_runtime.h>

typedef unsigned short u16;
typedef __attribute__((ext_vector_type(8))) __bf16 bf16x8;
typedef __attribute__((ext_vector_type(8))) unsigned short ushort8;
typedef __attribute__((ext_vector_type(4))) float f32x4;

#define MFMA16(a, b, c) __builtin_amdgcn_mfma_f32_16x16x32_bf16((a), (b), (c), 0, 0, 0)

__device__ __forceinline__ u16 f2bf(float f) {
  union { __bf16 h; u16 u; } cv;
  cv.h = (__bf16)f;  // native RNE cvt on gfx950
  return cv.u;
}

__device__ __forceinline__ void async16(const u16* g, u16* l) {
  __builtin_amdgcn_global_load_lds(
      (const __attribute__((address_space(1))) void*)g,
      (__attribute__((address_space(3))) void*)l, 16, 0, 0);
}

// ---------------- weight transpose fp32 [K][N] -> bf16 [N][K] ----------------
__global__ __launch_bounds__(256)
void transpose_bf16(const float* __restrict__ W, u16* __restrict__ Wt, int K, int N) {
  __shared__ float t[32][33];
  const int n0 = blockIdx.x * 32, k0 = blockIdx.y * 32;
  const int tx = threadIdx.x, ty = threadIdx.y;
  #pragma unroll
  for (int i = 0; i < 32; i += 8)
    t[ty + i][tx] = W[(size_t)(k0 + ty + i) * N + n0 + tx];
  __syncthreads();
  #pragma unroll
  for (int i = 0; i < 32; i += 8)
    Wt[(size_t)(n0 + ty + i) * K + k0 + tx] = f2bf(t[tx][ty + i]);
}

// ---------------- bf16 transpose for V: [B*H][2048][64] -> [B*H][64][2048] ----------------
__global__ __launch_bounds__(256)
void transpose_v(const u16* __restrict__ v, u16* __restrict__ vt) {
  __shared__ u16 t[64][72];
  const int bh = blockIdx.y, t0 = blockIdx.x * 64;
  const int tid = threadIdx.x;
  #pragma unroll
  for (int s = 0; s < 2; ++s) {
    const int idx = tid + s * 256;
    const int row = idx >> 3, ch = idx & 7;
    ushort8 d = *(const ushort8*)(v + ((size_t)bh * 2048 + t0 + row) * 64 + ch * 8);
    #pragma unroll
    for (int e = 0; e < 8; ++e) t[ch * 8 + e][row] = d[e];
  }
  __syncthreads();
  #pragma unroll
  for (int s = 0; s < 2; ++s) {
    const int idx = tid + s * 256;
    const int drow = idx >> 3, ch = idx & 7;
    ushort8 o = *(const ushort8*)(&t[drow][ch * 8]);
    *(ushort8*)(vt + ((size_t)bh * 64 + drow) * 2048 + t0 + ch * 8) = o;
  }
}

// ---------------- layernorm fp32 [4096][1024] -> bf16 ----------------
__global__ __launch_bounds__(256)
void ln_bf16(const float* __restrict__ X, const float* __restrict__ w,
             const float* __restrict__ bia, u16* __restrict__ out) {
  const int row = blockIdx.x, tid = threadIdx.x;
  const float4 v = ((const float4*)(X + (size_t)row * 1024))[tid];
  float s = v.x + v.y + v.z + v.w;
  float s2 = v.x * v.x + v.y * v.y + v.z * v.z + v.w * v.w;
  #pragma unroll
  for (int o = 32; o > 0; o >>= 1) { s += __shfl_down(s, o); s2 += __shfl_down(s2, o); }
  __shared__ float red[8];
  const int wv = tid >> 6, lane = tid & 63;
  if (lane == 0) { red[wv] = s; red[4 + wv] = s2; }
  __syncthreads();
  s = red[0] + red[1] + red[2] + red[3];
  s2 = red[4] + red[5] + red[6] + red[7];
  const float mean = s * (1.f / 1024.f);
  const float var = s2 * (1.f / 1024.f) - mean * mean;
  const float rstd = rsqrtf(var + 1e-5f);
  const float4 wv4 = ((const float4*)w)[tid];
  const float4 bv4 = ((const float4*)bia)[tid];
  ushort4 o;
  o.x = f2bf((v.x - mean) * rstd * wv4.x + bv4.x);
  o.y = f2bf((v.y - mean) * rstd * wv4.y + bv4.y);
  o.z = f2bf((v.z - mean) * rstd * wv4.z + bv4.z);
  o.w = f2bf((v.w - mean) * rstd * wv4.w + bv4.w);
  ((ushort4*)(out + (size_t)row * 1024))[tid] = o;
}

// ---------------- GEMM: C[M,N] = A[M,K] * Bt[N,K]^T ----------------
// BK=64, 128B LDS rows, XOR-8 chunk swizzle (conflict-free phase groups).
// MODE 0: qkv scatter (+bias) -> qo/ko/vo [B,H,T,d] bf16
// MODE 1: outF = resid + acc + bias (fp32)
// MODE 2: outB = gelu(acc + bias) (bf16)
// MODE 4: outF[z*M*N + ...] = acc (fp32 partial, split-K)
template <int MODE>
__global__ __launch_bounds__(256)
void gemm_bt(const u16* __restrict__ A, const u16* __restrict__ Bt,
             const float* __restrict__ bias, const float* __restrict__ resid,
             float* __restrict__ outF, u16* __restrict__ outB,
             u16* __restrict__ qo, u16* __restrict__ ko, u16* __restrict__ vo,
             int M, int N, int K, int kSlice) {
  __shared__ u16 As[128 * 64];
  __shared__ u16 Bs[128 * 64];
  const int tid = threadIdx.x;
  const int lane = tid & 63, wv = tid >> 6;
  const int l16 = lane & 15, quad = lane >> 4;
  const int wr = wv >> 1, wc = wv & 1;
  const int m0 = blockIdx.y * 128, n0 = blockIdx.x * 128;
  const int kBegin = blockIdx.z * kSlice, kEnd = kBegin + kSlice;
  const int srow = lane >> 3;
  const int sch = (lane & 7) ^ srow;

  f32x4 acc[4][4];
  const f32x4 fz = {0.f, 0.f, 0.f, 0.f};
  #pragma unroll
  for (int i = 0; i < 4; ++i)
    #pragma unroll
    for (int j = 0; j < 4; ++j) acc[i][j] = fz;

  for (int k0 = kBegin; k0 < kEnd; k0 += 64) {
    __syncthreads();
    #pragma unroll
    for (int s = 0; s < 4; ++s) {
      const int R = wv * 32 + s * 8;
      async16(A + (size_t)(m0 + R + srow) * K + k0 + sch * 8, As + R * 64);
      async16(Bt + (size_t)(n0 + R + srow) * K + k0 + sch * 8, Bs + R * 64);
    }
    __builtin_amdgcn_s_waitcnt(0xF70);  // vmcnt(0)
    __syncthreads();
    #pragma unroll
    for (int h = 0; h < 2; ++h) {
      bf16x8 af[4], bfr[4];
      #pragma unroll
      for (int i = 0; i < 4; ++i) {
        const int row = wr * 64 + i * 16 + l16;
        af[i] = *(const bf16x8*)(As + row * 64 + (((h * 4 + quad) ^ (l16 & 7)) * 8));
      }
      #pragma unroll
      for (int j = 0; j < 4; ++j) {
        const int row = wc * 64 + j * 16 + l16;
        bfr[j] = *(const bf16x8*)(Bs + row * 64 + (((h * 4 + quad) ^ (l16 & 7)) * 8));
      }
      #pragma unroll
      for (int i = 0; i < 4; ++i)
        #pragma unroll
        for (int j = 0; j < 4; ++j)
          acc[i][j] = MFMA16(af[i], bfr[j], acc[i][j]);
    }
  }

  #pragma unroll
  for (int i = 0; i < 4; ++i) {
    #pragma unroll
    for (int j = 0; j < 4; ++j) {
      const int col = n0 + wc * 64 + j * 16 + l16;
      const float bc = bias[col];
      #pragma unroll
      for (int r = 0; r < 4; ++r) {
        const int row = m0 + wr * 64 + i * 16 + quad * 4 + r;
        float v = acc[i][j][r];
        if (MODE != 4) v += bc;
        if (MODE == 0) {
          const int which = col >> 10, cc = col & 1023, hh = cc >> 6, dd = cc & 63;
          const int bb = row >> 11, t = row & 2047;
          const u16 bv = f2bf(v);
          const size_t o = ((size_t)(bb * 16 + hh) * 2048 + t) * 64 + dd;
          if (which == 0)
            qo[o] = bv;
          else if (which == 1)
            ko[o] = bv;
          else
            vo[o] = bv;
        } else if (MODE == 1) {
          outF[(size_t)row * N + col] = resid[(size_t)row * N + col] + v;
        } else if (MODE == 2) {
          const float x3 = v * v * v;
          const float u = 0.7978845608028654f * (v + 0.044715f * x3);
          const float e = __expf(2.f * u);
          const float th = 1.f - 2.f / (e + 1.f);
          outB[(size_t)row * N + col] = f2bf(0.5f * v * (1.f + th));
        } else {
          outF[(size_t)blockIdx.z * M * N + (size_t)row * N + col] = v;
        }
      }
    }
  }
}

// ---------------- split-K reduce: out = resid + bias + P0 + P1 ----------------
__global__ __launch_bounds__(256)
void reduce2(const float* __restrict__ P, const float* __restrict__ resid,
             const float* __restrict__ bias, float* __restrict__ out, int MN, int N) {
  const int idx4 = blockIdx.x * 256 + threadIdx.x;
  const size_t s = (size_t)MN >> 2;
  const float4 a = ((const float4*)P)[idx4];
  const float4 b = ((const float4*)P)[idx4 + s];
  const float4 r = ((const float4*)resid)[idx4];
  const float4 bb = ((const float4*)bias)[idx4 & (N / 4 - 1)];
  float4 o;
  o.x = r.x + a.x + b.x + bb.x;
  o.y = r.y + a.y + b.y + bb.y;
  o.z = r.z + a.z + b.z + bb.z;
  o.w = r.w + a.w + b.w + bb.w;
  ((float4*)out)[idx4] = o;
}

// ---------------- flash attention (causal), balanced pairing, S^T softmax ----------------
// block = (b,h, pair p, half): 64 q-rows of BOTH q-tiles p and 15-p.
// S^T = K Q^T: in C-layout each lane owns ONE q-row (col=lane&15) -> scalar m/l state,
// 2-shuffle reductions, packed b64 P stores.
__global__ __launch_bounds__(256)
void attn(const u16* __restrict__ Q, const u16* __restrict__ Kg,
          const u16* __restrict__ Vt, u16* __restrict__ ctx) {
  __shared__ u16 Ks[128 * 64];   // [key][64], 8-chunk xor-swizzled by key&7
  __shared__ u16 Vs[64 * 128];   // [d][128], 16-chunk xor-swizzled by d&15
  __shared__ u16 Ps[64 * 128];   // [local q][128], 16-chunk xor-swizzled by q&15
  const int px = blockIdx.x;
  const int pair = px >> 1, half = px & 1;
  const int qt0 = pair, qt1 = 15 - pair;
  const int bh = blockIdx.y;
  const int b = bh >> 4, h = bh & 15;
  const int tid = threadIdx.x;
  const int lane = tid & 63, wv = tid >> 6;
  const int l16 = lane & 15, quad = lane >> 4;
  const int rb = half * 64 + wv * 16;
  const float S2 = 0.18033688011112042f;  // 0.125 * log2(e)
  const u16* Qb = Q + (size_t)bh * 2048 * 64;
  const u16* Kb = Kg + (size_t)bh * 2048 * 64;
  const u16* Vb = Vt + (size_t)bh * 64 * 2048;

  bf16x8 qf[2][2];
  #pragma unroll
  for (int t = 0; t < 2; ++t)
    #pragma unroll
    for (int c = 0; c < 2; ++c)
      qf[t][c] = *(const bf16x8*)(Qb + (size_t)((t ? qt1 : qt0) * 128 + rb + l16) * 64 +
                                  c * 32 + quad * 8);

  f32x4 octx[2][4];
  const f32x4 fz = {0.f, 0.f, 0.f, 0.f};
  #pragma unroll
  for (int t = 0; t < 2; ++t)
    #pragma unroll
    for (int jd = 0; jd < 4; ++jd) octx[t][jd] = fz;
  float mi2[2] = {-1e30f, -1e30f};  // per-lane: this lane's q-row (base-2 domain)
  float li[2] = {0.f, 0.f};

  for (int kt = 0; kt <= qt1; ++kt) {
    __syncthreads();
    #pragma unroll
    for (int s = 0; s < 4; ++s) {
      const int cid = tid + s * 256;
      {
        const int key = cid >> 3, ch = cid & 7;
        ushort8 d = *(const ushort8*)(Kb + (size_t)(kt * 128 + key) * 64 + ch * 8);
        *(ushort8*)(Ks + key * 64 + ((ch ^ (key & 7)) * 8)) = d;
      }
      {
        const int dd = cid >> 4, ch = cid & 15;
        ushort8 d = *(const ushort8*)(Vb + (size_t)dd * 2048 + kt * 128 + ch * 8);
        *(ushort8*)(Vs + dd * 128 + ((ch ^ (dd & 15)) * 8)) = d;
      }
    }
    __syncthreads();

    #pragma unroll
    for (int t = 0; t < 2; ++t) {
      const int qt = t ? qt1 : qt0;
      if (kt > qt) continue;

      // S^T: A=K-frag, B=Q-frag -> C[row=key, col=q-row(lane&15)]
      f32x4 sa[8];
      #pragma unroll
      for (int j = 0; j < 8; ++j) {
        const int key7 = l16 & 7;
        bf16x8 kf0 = *(const bf16x8*)(Ks + (16 * j + l16) * 64 + ((quad ^ key7) * 8));
        bf16x8 kf1 = *(const bf16x8*)(Ks + (16 * j + l16) * 64 + (((4 + quad) ^ key7) * 8));
        f32x4 tt = MFMA16(kf0, qf[t][0], fz);
        sa[j] = MFMA16(kf1, qf[t][1], tt);
      }
      if (kt == qt) {
        const int rg = rb + l16;  // my q-row (local within tile)
        #pragma unroll
        for (int j = 0; j < 8; ++j)
          #pragma unroll
          for (int r = 0; r < 4; ++r)
            if (j * 16 + quad * 4 + r > rg) sa[j][r] = -1e30f;
      }
      // per-lane online softmax for my single q-row
      float mx = -1e30f;
      #pragma unroll
      for (int j = 0; j < 8; ++j)
        #pragma unroll
        for (int r = 0; r < 4; ++r) mx = fmaxf(mx, sa[j][r]);
      mx = fmaxf(mx, __shfl_xor(mx, 16));
      mx = fmaxf(mx, __shfl_xor(mx, 32));
      mx *= S2;
      const float mn = fmaxf(mi2[t], mx);
      const float al = __builtin_amdgcn_exp2f(mi2[t] - mn);
      mi2[t] = mn;
      const int row_local = wv * 16 + l16;
      float rs = 0.f;
      #pragma unroll
      for (int j = 0; j < 8; ++j) {
        ushort4 w4;
        float p0 = __builtin_amdgcn_exp2f(sa[j][0] * S2 - mn);
        float p1 = __builtin_amdgcn_exp2f(sa[j][1] * S2 - mn);
        float p2 = __builtin_amdgcn_exp2f(sa[j][2] * S2 - mn);
        float p3 = __builtin_amdgcn_exp2f(sa[j][3] * S2 - mn);
        rs += (p0 + p1) + (p2 + p3);
        w4.x = f2bf(p0); w4.y = f2bf(p1); w4.z = f2bf(p2); w4.w = f2bf(p3);
        const int c = 2 * j + (quad >> 1);  // 8-elem chunk of keys j*16+quad*4..+3
        *(ushort4*)(Ps + row_local * 128 + ((c ^ l16) * 8) + (quad & 1) * 4) = w4;
      }
      rs += __shfl_xor(rs, 16);
      rs += __shfl_xor(rs, 32);
      li[t] = li[t] * al + rs;
      // octx rows are rb+quad*4+r -> broadcast that row's alpha (held at lane l16=quad*4+r)
      #pragma unroll
      for (int r = 0; r < 4; ++r) {
        const float alr = __shfl(al, quad * 4 + r);
        #pragma unroll
        for (int jd = 0; jd < 4; ++jd) octx[t][jd][r] *= alr;
      }
      // ctx += P V (lane reads only rows it wrote within its wave's 16-row band)
      #pragma unroll
      for (int c = 0; c < 4; ++c) {
        bf16x8 pf = *(const bf16x8*)(Ps + row_local * 128 + (((c * 4 + quad) ^ l16) * 8));
        #pragma unroll
        for (int jd = 0; jd < 4; ++jd) {
          const int dd = jd * 16 + l16;
          bf16x8 vf = *(const bf16x8*)(Vs + dd * 128 + (((c * 4 + quad) ^ (dd & 15)) * 8));
          octx[t][jd] = MFMA16(pf, vf, octx[t][jd]);
        }
      }
    }
  }
  // epilogue: divide by l (broadcast per octx row), write [B][T][H*d] bf16
  #pragma unroll
  for (int t = 0; t < 2; ++t) {
    const int qt = t ? qt1 : qt0;
    #pragma unroll
    for (int r = 0; r < 4; ++r) {
      const float lr = __builtin_amdgcn_rcpf(__shfl(li[t], quad * 4 + r));
      const int rowg = qt * 128 + rb + quad * 4 + r;
      #pragma unroll
      for (int jd = 0; jd < 4; ++jd) {
        const int col = h * 64 + jd * 16 + l16;
        ctx[((size_t)b * 2048 + rowg) * 1024 + col] = f2bf(octx[t][jd][r] * lr);
      }
    }
  }
}

// ---------------- launch ----------------
extern "C" void kernel_launch(void* const* d_in, const int* in_sizes, int n_in,
                              void* d_out, int out_size, void* d_ws, size_t ws_size,
                              hipStream_t stream) {
  (void)in_sizes; (void)n_in; (void)out_size; (void)ws_size;
  const float* x      = (const float*)d_in[0];
  const float* ln1_w  = (const float*)d_in[1];
  const float* ln1_b  = (const float*)d_in[2];
  const float* w_qkv  = (const float*)d_in[3];
  const float* b_qkv  = (const float*)d_in[4];
  const float* w_attn = (const float*)d_in[5];
  const float* b_attn = (const float*)d_in[6];
  const float* ln2_w  = (const float*)d_in[7];
  const float* ln2_b  = (const float*)d_in[8];
  const float* w_fc   = (const float*)d_in[9];
  const float* b_fc   = (const float*)d_in[10];
  const float* w_proj = (const float*)d_in[11];
  const float* b_proj = (const float*)d_in[12];
  float* out = (float*)d_out;

  char* ws = (char*)d_ws;
  size_t off = 0;
  auto alloc = [&](size_t n) {
    char* p = ws + off;
    off += (n + 255) & ~(size_t)255;
    return p;
  };
  u16* h1     = (u16*)alloc(4096ull * 1024 * 2);
  u16* wqkvT  = (u16*)alloc(3072ull * 1024 * 2);
  u16* wattnT = (u16*)alloc(1024ull * 1024 * 2);
  u16* wfcT   = (u16*)alloc(4096ull * 1024 * 2);
  u16* wprojT = (u16*)alloc(1024ull * 4096 * 2);
  u16* q      = (u16*)alloc(4096ull * 1024 * 2);
  u16* k      = (u16*)alloc(4096ull * 1024 * 2);
  u16* vT     = (u16*)alloc(4096ull * 1024 * 2);
  u16* ctxb   = (u16*)alloc(4096ull * 1024 * 2);
  float* out1 = (float*)alloc(4096ull * 1024 * 4);
  u16* h2     = (u16*)alloc(4096ull * 1024 * 2);
  u16* fco    = (u16*)alloc(4096ull * 4096 * 2);

  u16* vtmp = ctxb;
  float* projP = (float*)q;

  const dim3 tb(32, 8);
  transpose_bf16<<<dim3(3072 / 32, 1024 / 32), tb, 0, stream>>>(w_qkv, wqkvT, 1024, 3072);
  transpose_bf16<<<dim3(1024 / 32, 1024 / 32), tb, 0, stream>>>(w_attn, wattnT, 1024, 1024);
  transpose_bf16<<<dim3(4096 / 32, 1024 / 32), tb, 0, stream>>>(w_fc, wfcT, 1024, 4096);
  transpose_bf16<<<dim3(1024 / 32, 4096 / 32), tb, 0, stream>>>(w_proj, wprojT, 4096, 1024);

  ln_bf16<<<4096, 256, 0, stream>>>(x, ln1_w, ln1_b, h1);

  gemm_bt<0><<<dim3(24, 32, 1), 256, 0, stream>>>(h1, wqkvT, b_qkv, nullptr, nullptr,
                                                  nullptr, q, k, vtmp, 4096, 3072, 1024, 1024);

  transpose_v<<<dim3(32, 32), 256, 0, stream>>>(vtmp, vT);

  attn<<<dim3(16, 32), 256, 0, stream>>>(q, k, vT, ctxb);

  gemm_bt<1><<<dim3(8, 32, 1), 256, 0, stream>>>(ctxb, wattnT, b_attn, x, out1, nullptr,
                                                 nullptr, nullptr, nullptr, 4096, 1024, 1024, 1024);

  ln_bf16<<<4096, 256, 0, stream>>>(out1, ln2_w, ln2_b, h2);

  gemm_bt<2><<<dim3(32, 32, 1), 256, 0, stream>>>(h2, wfcT, b_fc, nullptr, nullptr, fco,
                                                  nullptr, nullptr, nullptr, 4096, 4096, 1024, 1024);

  gemm_bt<4><<<dim3(8, 32, 2), 256, 0, stream>>>(fco, wprojT, b_proj, nullptr, projP, nullptr,
                                                 nullptr, nullptr, nullptr, 4096, 1024, 4096, 2048);

  reduce2<<<4096, 256, 0, stream>>>(projP, out1, b_proj, out, 4096 * 1024, 1024);
}

// Round 5
// 372.298 us; speedup vs baseline: 1.4178x; 1.0038x over previous
//
#include <hip/hip_runtime.h>

typedef unsigned short u16;
typedef __attribute__((ext_vector_type(8))) __bf16 bf16x8;
typedef __attribute__((ext_vector_type(8))) unsigned short ushort8;
typedef __attribute__((ext_vector_type(4))) float f32x4;

#define MFMA16(a, b, c) __builtin_amdgcn_mfma_f32_16x16x32_bf16((a), (b), (c), 0, 0, 0)

__device__ __forceinline__ u16 f2bf(float f) {
  union { __bf16 h; u16 u; } cv;
  cv.h = (__bf16)f;
  return cv.u;
}

__device__ __forceinline__ void async16(const u16* g, u16* l) {
  __builtin_amdgcn_global_load_lds(
      (const __attribute__((address_space(1))) void*)g,
      (__attribute__((address_space(3))) void*)l, 16, 0, 0);
}

// ---------------- weight transpose fp32 [K][N] -> bf16 [N][K] ----------------
__global__ __launch_bounds__(256)
void transpose_bf16(const float* __restrict__ W, u16* __restrict__ Wt, int K, int N) {
  __shared__ float t[32][33];
  const int n0 = blockIdx.x * 32, k0 = blockIdx.y * 32;
  const int tx = threadIdx.x, ty = threadIdx.y;
  #pragma unroll
  for (int i = 0; i < 32; i += 8)
    t[ty + i][tx] = W[(size_t)(k0 + ty + i) * N + n0 + tx];
  __syncthreads();
  #pragma unroll
  for (int i = 0; i < 32; i += 8)
    Wt[(size_t)(n0 + ty + i) * K + k0 + tx] = f2bf(t[tx][ty + i]);
}

// ---------------- bf16 transpose for V: [B*H][2048][64] -> [B*H][64][2048] ----------------
__global__ __launch_bounds__(256)
void transpose_v(const u16* __restrict__ v, u16* __restrict__ vt) {
  __shared__ u16 t[64][72];
  const int bh = blockIdx.y, t0 = blockIdx.x * 64;
  const int tid = threadIdx.x;
  #pragma unroll
  for (int s = 0; s < 2; ++s) {
    const int idx = tid + s * 256;
    const int row = idx >> 3, ch = idx & 7;
    ushort8 d = *(const ushort8*)(v + ((size_t)bh * 2048 + t0 + row) * 64 + ch * 8);
    #pragma unroll
    for (int e = 0; e < 8; ++e) t[ch * 8 + e][row] = d[e];
  }
  __syncthreads();
  #pragma unroll
  for (int s = 0; s < 2; ++s) {
    const int idx = tid + s * 256;
    const int drow = idx >> 3, ch = idx & 7;
    ushort8 o = *(const ushort8*)(&t[drow][ch * 8]);
    *(ushort8*)(vt + ((size_t)bh * 64 + drow) * 2048 + t0 + ch * 8) = o;
  }
}

// ---------------- layernorm fp32 [4096][1024] -> bf16 ----------------
__global__ __launch_bounds__(256)
void ln_bf16(const float* __restrict__ X, const float* __restrict__ w,
             const float* __restrict__ bia, u16* __restrict__ out) {
  const int row = blockIdx.x, tid = threadIdx.x;
  const float4 v = ((const float4*)(X + (size_t)row * 1024))[tid];
  float s = v.x + v.y + v.z + v.w;
  float s2 = v.x * v.x + v.y * v.y + v.z * v.z + v.w * v.w;
  #pragma unroll
  for (int o = 32; o > 0; o >>= 1) { s += __shfl_down(s, o); s2 += __shfl_down(s2, o); }
  __shared__ float red[8];
  const int wv = tid >> 6, lane = tid & 63;
  if (lane == 0) { red[wv] = s; red[4 + wv] = s2; }
  __syncthreads();
  s = red[0] + red[1] + red[2] + red[3];
  s2 = red[4] + red[5] + red[6] + red[7];
  const float mean = s * (1.f / 1024.f);
  const float var = s2 * (1.f / 1024.f) - mean * mean;
  const float rstd = rsqrtf(var + 1e-5f);
  const float4 wv4 = ((const float4*)w)[tid];
  const float4 bv4 = ((const float4*)bia)[tid];
  ushort4 o;
  o.x = f2bf((v.x - mean) * rstd * wv4.x + bv4.x);
  o.y = f2bf((v.y - mean) * rstd * wv4.y + bv4.y);
  o.z = f2bf((v.z - mean) * rstd * wv4.z + bv4.z);
  o.w = f2bf((v.w - mean) * rstd * wv4.w + bv4.w);
  ((ushort4*)(out + (size_t)row * 1024))[tid] = o;
}

// ---------------- GEMM: C[M,N] = A[M,K] * Bt[N,K]^T ----------------
// BK=64, 128B LDS rows, XOR-8 chunk swizzle.
// MODE 0: qkv scatter (+bias) -> qo/ko/vo [B,H,T,d] bf16
// MODE 2: outB = gelu(acc + bias) (bf16)
// MODE 4: outF[z*M*N + ...] = acc (fp32 partial, split-K)
template <int MODE>
__global__ __launch_bounds__(256)
void gemm_bt(const u16* __restrict__ A, const u16* __restrict__ Bt,
             const float* __restrict__ bias, const float* __restrict__ resid,
             float* __restrict__ outF, u16* __restrict__ outB,
             u16* __restrict__ qo, u16* __restrict__ ko, u16* __restrict__ vo,
             int M, int N, int K, int kSlice) {
  __shared__ u16 As[128 * 64];
  __shared__ u16 Bs[128 * 64];
  const int tid = threadIdx.x;
  const int lane = tid & 63, wv = tid >> 6;
  const int l16 = lane & 15, quad = lane >> 4;
  const int wr = wv >> 1, wc = wv & 1;
  const int m0 = blockIdx.y * 128, n0 = blockIdx.x * 128;
  const int kBegin = blockIdx.z * kSlice, kEnd = kBegin + kSlice;
  const int srow = lane >> 3;
  const int sch = (lane & 7) ^ srow;

  f32x4 acc[4][4];
  const f32x4 fz = {0.f, 0.f, 0.f, 0.f};
  #pragma unroll
  for (int i = 0; i < 4; ++i)
    #pragma unroll
    for (int j = 0; j < 4; ++j) acc[i][j] = fz;

  for (int k0 = kBegin; k0 < kEnd; k0 += 64) {
    __syncthreads();
    #pragma unroll
    for (int s = 0; s < 4; ++s) {
      const int R = wv * 32 + s * 8;
      async16(A + (size_t)(m0 + R + srow) * K + k0 + sch * 8, As + R * 64);
      async16(Bt + (size_t)(n0 + R + srow) * K + k0 + sch * 8, Bs + R * 64);
    }
    __builtin_amdgcn_s_waitcnt(0xF70);  // vmcnt(0)
    __syncthreads();
    #pragma unroll
    for (int h = 0; h < 2; ++h) {
      bf16x8 af[4], bfr[4];
      #pragma unroll
      for (int i = 0; i < 4; ++i) {
        const int row = wr * 64 + i * 16 + l16;
        af[i] = *(const bf16x8*)(As + row * 64 + (((h * 4 + quad) ^ (l16 & 7)) * 8));
      }
      #pragma unroll
      for (int j = 0; j < 4; ++j) {
        const int row = wc * 64 + j * 16 + l16;
        bfr[j] = *(const bf16x8*)(Bs + row * 64 + (((h * 4 + quad) ^ (l16 & 7)) * 8));
      }
      #pragma unroll
      for (int i = 0; i < 4; ++i)
        #pragma unroll
        for (int j = 0; j < 4; ++j)
          acc[i][j] = MFMA16(af[i], bfr[j], acc[i][j]);
    }
  }

  #pragma unroll
  for (int i = 0; i < 4; ++i) {
    #pragma unroll
    for (int j = 0; j < 4; ++j) {
      const int col = n0 + wc * 64 + j * 16 + l16;
      const float bc = bias[col];
      #pragma unroll
      for (int r = 0; r < 4; ++r) {
        const int row = m0 + wr * 64 + i * 16 + quad * 4 + r;
        float v = acc[i][j][r];
        if (MODE != 4) v += bc;
        if (MODE == 0) {
          const int which = col >> 10, cc = col & 1023, hh = cc >> 6, dd = cc & 63;
          const int bb = row >> 11, t = row & 2047;
          const u16 bv = f2bf(v);
          const size_t o = ((size_t)(bb * 16 + hh) * 2048 + t) * 64 + dd;
          if (which == 0)
            qo[o] = bv;
          else if (which == 1)
            ko[o] = bv;
          else
            vo[o] = bv;
        } else if (MODE == 2) {
          const float x3 = v * v * v;
          const float u = 0.7978845608028654f * (v + 0.044715f * x3);
          const float e = __expf(2.f * u);
          const float th = 1.f - 2.f / (e + 1.f);
          outB[(size_t)row * N + col] = f2bf(0.5f * v * (1.f + th));
        } else {
          outF[(size_t)blockIdx.z * M * N + (size_t)row * N + col] = v;
        }
      }
    }
  }
}

// ---------------- split-K reduce: out = resid + bias + P0 + P1 ----------------
__global__ __launch_bounds__(256)
void reduce2(const float* __restrict__ P, const float* __restrict__ resid,
             const float* __restrict__ bias, float* __restrict__ out, int MN, int N) {
  const int idx4 = blockIdx.x * 256 + threadIdx.x;
  const size_t s = (size_t)MN >> 2;
  const float4 a = ((const float4*)P)[idx4];
  const float4 b = ((const float4*)P)[idx4 + s];
  const float4 r = ((const float4*)resid)[idx4];
  const float4 bb = ((const float4*)bias)[idx4 & (N / 4 - 1)];
  float4 o;
  o.x = r.x + a.x + b.x + bb.x;
  o.y = r.y + a.y + b.y + bb.y;
  o.z = r.z + a.z + b.z + bb.z;
  o.w = r.w + a.w + b.w + bb.w;
  ((float4*)out)[idx4] = o;
}

// ---------------- flash attention (causal), S^T softmax, async dbuf-K staging ----------------
// block = (b,h,pair,half): 64 q-rows of tiles qt0=pair and qt1=15-pair.
// Ks double-buffered (prefetch kt+1 overlaps compute); V staged async at iter top.
// kf/vf fragments shared across both q-tiles where possible.
__global__ __launch_bounds__(256)
void attn(const u16* __restrict__ Q, const u16* __restrict__ Kg,
          const u16* __restrict__ Vt, u16* __restrict__ ctx) {
  __shared__ u16 Ks[2][128 * 64];  // [key][64], chunk slot s holds global chunk s^(key&7)
  __shared__ u16 Vs[64 * 128];     // [d][128], chunk slot s holds global chunk s^(d&15)
  __shared__ u16 Ps[64 * 128];     // [local q][128], chunk swizzle by q&15
  const int px = blockIdx.x;
  const int pair = px >> 1, half = px & 1;
  const int qt0 = pair, qt1 = 15 - pair;
  const int bh = blockIdx.y;
  const int b = bh >> 4, h = bh & 15;
  const int tid = threadIdx.x;
  const int lane = tid & 63, wv = tid >> 6;
  const int l16 = lane & 15, quad = lane >> 4;
  const int rb = half * 64 + wv * 16;
  const int row_local = wv * 16 + l16;
  const float S2 = 0.18033688011112042f;  // 0.125 * log2(e)
  const u16* Qb = Q + (size_t)bh * 2048 * 64;
  const u16* Kb = Kg + (size_t)bh * 2048 * 64;
  const u16* Vb = Vt + (size_t)bh * 64 * 2048;

  bf16x8 qf[2][2];
  #pragma unroll
  for (int t = 0; t < 2; ++t)
    #pragma unroll
    for (int c = 0; c < 2; ++c)
      qf[t][c] = *(const bf16x8*)(Qb + (size_t)((t ? qt1 : qt0) * 128 + rb + l16) * 64 +
                                  c * 32 + quad * 8);

  f32x4 octx[2][4];
  const f32x4 fz = {0.f, 0.f, 0.f, 0.f};
  #pragma unroll
  for (int t = 0; t < 2; ++t)
    #pragma unroll
    for (int jd = 0; jd < 4; ++jd) octx[t][jd] = fz;
  float mi2[2] = {-1e30f, -1e30f};
  float li[2] = {0.f, 0.f};

  // staging lambdas (async, swizzle applied on global source chunk)
  const int kRow = lane >> 3, kCh = (lane & 7) ^ ((lane >> 3) & 7);
  const int vRow = lane >> 4;
  auto stageK = [&](int kt, int buf) {
    #pragma unroll
    for (int s = 0; s < 4; ++s) {
      const int R = wv * 32 + s * 8;
      async16(Kb + (size_t)(kt * 128 + R + kRow) * 64 + kCh * 8, &Ks[buf][R * 64]);
    }
  };
  auto stageV = [&](int kt) {
    #pragma unroll
    for (int s = 0; s < 4; ++s) {
      const int D = wv * 16 + s * 4;
      const int dd = D + vRow;
      const int sch = (lane & 15) ^ (dd & 15);
      async16(Vb + (size_t)dd * 2048 + kt * 128 + sch * 8, &Vs[D * 128]);
    }
  };

  // softmax + P-write for one tile; sa consumed
  auto softmax_t = [&](int t, f32x4* sa, int kt, int qt) {
    if (kt == qt) {
      const int rg = rb + l16;
      #pragma unroll
      for (int j = 0; j < 8; ++j)
        #pragma unroll
        for (int r = 0; r < 4; ++r)
          if (j * 16 + quad * 4 + r > rg) sa[j][r] = -1e30f;
    }
    float mx = -1e30f;
    #pragma unroll
    for (int j = 0; j < 8; ++j)
      #pragma unroll
      for (int r = 0; r < 4; ++r) mx = fmaxf(mx, sa[j][r]);
    mx = fmaxf(mx, __shfl_xor(mx, 16));
    mx = fmaxf(mx, __shfl_xor(mx, 32));
    mx *= S2;
    const float mn = fmaxf(mi2[t], mx);
    const float al = __builtin_amdgcn_exp2f(mi2[t] - mn);
    mi2[t] = mn;
    float rs = 0.f;
    #pragma unroll
    for (int j = 0; j < 8; ++j) {
      ushort4 w4;
      float p0 = __builtin_amdgcn_exp2f(sa[j][0] * S2 - mn);
      float p1 = __builtin_amdgcn_exp2f(sa[j][1] * S2 - mn);
      float p2 = __builtin_amdgcn_exp2f(sa[j][2] * S2 - mn);
      float p3 = __builtin_amdgcn_exp2f(sa[j][3] * S2 - mn);
      rs += (p0 + p1) + (p2 + p3);
      w4.x = f2bf(p0); w4.y = f2bf(p1); w4.z = f2bf(p2); w4.w = f2bf(p3);
      const int c = 2 * j + (quad >> 1);
      *(ushort4*)(Ps + row_local * 128 + ((c ^ l16) * 8) + (quad & 1) * 4) = w4;
    }
    rs += __shfl_xor(rs, 16);
    rs += __shfl_xor(rs, 32);
    li[t] = li[t] * al + rs;
    #pragma unroll
    for (int r = 0; r < 4; ++r) {
      const float alr = __shfl(al, quad * 4 + r);
      #pragma unroll
      for (int jd = 0; jd < 4; ++jd) octx[t][jd][r] *= alr;
    }
  };
  auto pv_t = [&](int t) {
    #pragma unroll
    for (int c = 0; c < 4; ++c) {
      bf16x8 pf = *(const bf16x8*)(Ps + row_local * 128 + (((c * 4 + quad) ^ l16) * 8));
      #pragma unroll
      for (int jd = 0; jd < 4; ++jd) {
        const int dd = jd * 16 + l16;
        bf16x8 vf = *(const bf16x8*)(Vs + dd * 128 + (((c * 4 + quad) ^ (dd & 15)) * 8));
        octx[t][jd] = MFMA16(pf, vf, octx[t][jd]);
      }
    }
  };

  stageK(0, 0);
  __builtin_amdgcn_s_waitcnt(0xF70);  // vmcnt(0)
  __syncthreads();

  for (int kt = 0; kt <= qt1; ++kt) {
    const int cur = kt & 1;
    stageV(kt);
    if (kt < qt1) stageK(kt + 1, cur ^ 1);
    const bool both = (kt <= qt0);

    // QK^T (S^T layout) for active tiles — kf read once, shared
    f32x4 sa0[8], sa1[8];
    const u16* KsC = Ks[cur];
    #pragma unroll
    for (int j = 0; j < 8; ++j) {
      const int key7 = l16 & 7;
      bf16x8 kf0 = *(const bf16x8*)(KsC + (16 * j + l16) * 64 + ((quad ^ key7) * 8));
      bf16x8 kf1 = *(const bf16x8*)(KsC + (16 * j + l16) * 64 + (((4 + quad) ^ key7) * 8));
      sa1[j] = MFMA16(kf1, qf[1][1], MFMA16(kf0, qf[1][0], fz));
      if (both) sa0[j] = MFMA16(kf1, qf[0][1], MFMA16(kf0, qf[0][0], fz));
    }

    // first active tile's softmax overlaps the V/K async loads
    if (both)
      softmax_t(0, sa0, kt, qt0);
    else
      softmax_t(1, sa1, kt, qt1);

    __builtin_amdgcn_s_waitcnt(0xF70);  // vmcnt(0): Vs (and K prefetch) landed
    __syncthreads();

    if (both) {
      pv_t(0);
      softmax_t(1, sa1, kt, qt1);  // overwrites Ps after pv_t(0) reads (same-wave order)
      pv_t(1);
    } else {
      pv_t(1);
    }
    __syncthreads();  // Vs consumed by all waves before next iter restages
  }

  // epilogue: /l, write [B][T][H*d] bf16
  #pragma unroll
  for (int t = 0; t < 2; ++t) {
    const int qt = t ? qt1 : qt0;
    #pragma unroll
    for (int r = 0; r < 4; ++r) {
      const float lr = __builtin_amdgcn_rcpf(__shfl(li[t], quad * 4 + r));
      const int rowg = qt * 128 + rb + quad * 4 + r;
      #pragma unroll
      for (int jd = 0; jd < 4; ++jd) {
        const int col = h * 64 + jd * 16 + l16;
        ctx[((size_t)b * 2048 + rowg) * 1024 + col] = f2bf(octx[t][jd][r] * lr);
      }
    }
  }
}

// ---------------- launch ----------------
extern "C" void kernel_launch(void* const* d_in, const int* in_sizes, int n_in,
                              void* d_out, int out_size, void* d_ws, size_t ws_size,
                              hipStream_t stream) {
  (void)in_sizes; (void)n_in; (void)out_size; (void)ws_size;
  const float* x      = (const float*)d_in[0];
  const float* ln1_w  = (const float*)d_in[1];
  const float* ln1_b  = (const float*)d_in[2];
  const float* w_qkv  = (const float*)d_in[3];
  const float* b_qkv  = (const float*)d_in[4];
  const float* w_attn = (const float*)d_in[5];
  const float* b_attn = (const float*)d_in[6];
  const float* ln2_w  = (const float*)d_in[7];
  const float* ln2_b  = (const float*)d_in[8];
  const float* w_fc   = (const float*)d_in[9];
  const float* b_fc   = (const float*)d_in[10];
  const float* w_proj = (const float*)d_in[11];
  const float* b_proj = (const float*)d_in[12];
  float* out = (float*)d_out;

  char* ws = (char*)d_ws;
  size_t off = 0;
  auto alloc = [&](size_t n) {
    char* p = ws + off;
    off += (n + 255) & ~(size_t)255;
    return p;
  };
  u16* h1     = (u16*)alloc(4096ull * 1024 * 2);
  u16* wqkvT  = (u16*)alloc(3072ull * 1024 * 2);
  u16* wattnT = (u16*)alloc(1024ull * 1024 * 2);
  u16* wfcT   = (u16*)alloc(4096ull * 1024 * 2);
  u16* wprojT = (u16*)alloc(1024ull * 4096 * 2);
  u16* q      = (u16*)alloc(4096ull * 1024 * 2);
  u16* k      = (u16*)alloc(4096ull * 1024 * 2);
  u16* vT     = (u16*)alloc(4096ull * 1024 * 2);
  u16* ctxb   = (u16*)alloc(4096ull * 1024 * 2);
  float* out1 = (float*)alloc(4096ull * 1024 * 4);
  u16* h2     = (u16*)alloc(4096ull * 1024 * 2);
  u16* fco    = (u16*)alloc(4096ull * 4096 * 2);

  u16* vtmp = ctxb;             // dead until attn; raw V [B,H,T,d]
  float* apP = (float*)fco;     // fco dead until FC: attn-proj split-K partials (32 MB)
  float* projP = (float*)q;     // q..ctxb (32 MB) dead after attn-proj: proj partials

  const dim3 tb(32, 8);
  transpose_bf16<<<dim3(3072 / 32, 1024 / 32), tb, 0, stream>>>(w_qkv, wqkvT, 1024, 3072);
  transpose_bf16<<<dim3(1024 / 32, 1024 / 32), tb, 0, stream>>>(w_attn, wattnT, 1024, 1024);
  transpose_bf16<<<dim3(4096 / 32, 1024 / 32), tb, 0, stream>>>(w_fc, wfcT, 1024, 4096);
  transpose_bf16<<<dim3(1024 / 32, 4096 / 32), tb, 0, stream>>>(w_proj, wprojT, 4096, 1024);

  ln_bf16<<<4096, 256, 0, stream>>>(x, ln1_w, ln1_b, h1);

  gemm_bt<0><<<dim3(24, 32, 1), 256, 0, stream>>>(h1, wqkvT, b_qkv, nullptr, nullptr,
                                                  nullptr, q, k, vtmp, 4096, 3072, 1024, 1024);

  transpose_v<<<dim3(32, 32), 256, 0, stream>>>(vtmp, vT);

  attn<<<dim3(16, 32), 256, 0, stream>>>(q, k, vT, ctxb);

  // attn-proj: split-K=2 partials into fco, fused reduce + bias + residual(x) -> out1
  gemm_bt<4><<<dim3(8, 32, 2), 256, 0, stream>>>(ctxb, wattnT, b_attn, nullptr, apP, nullptr,
                                                 nullptr, nullptr, nullptr, 4096, 1024, 1024, 512);
  reduce2<<<4096, 256, 0, stream>>>(apP, x, b_attn, out1, 4096 * 1024, 1024);

  ln_bf16<<<4096, 256, 0, stream>>>(out1, ln2_w, ln2_b, h2);

  gemm_bt<2><<<dim3(32, 32, 1), 256, 0, stream>>>(h2, wfcT, b_fc, nullptr, nullptr, fco,
                                                  nullptr, nullptr, nullptr, 4096, 4096, 1024, 1024);

  gemm_bt<4><<<dim3(8, 32, 2), 256, 0, stream>>>(fco, wprojT, b_proj, nullptr, projP, nullptr,
                                                 nullptr, nullptr, nullptr, 4096, 1024, 4096, 2048);

  reduce2<<<4096, 256, 0, stream>>>(projP, out1, b_proj, out, 4096 * 1024, 1024);
}